// Round 1
// baseline (1437.546 us; speedup 1.0000x reference)
//
#include <hip/hip_runtime.h>
#include <hip/hip_bf16.h>
#include <math.h>

#define B_    2
#define Q_    1024
#define H_    32
#define KVH_  8
#define HD_   64
#define HS_   2048
#define NREP_ 4
#define KIN_  (2*HS_)            // 4096
#define M_    (B_*Q_)            // 2048
#define QKVN_ (H_*HD_ + 2*KVH_*HD_)  // 3072
#define AOW_  (H_*HD_)           // 2048
#define SCALE_ 0.125f            // 1/sqrt(64)

// ---------------- NT SGEMM: C[m][col_off+n] = sum_k A[m][k] * W[n][k] ----------------
// 64x64 tile per 256-thread block, BK=16, 4x4 per thread. fp32.
__global__ __launch_bounds__(256) void sgemm_nt(
    const float* __restrict__ A, const float* __restrict__ W,
    float* __restrict__ C, int K, int ldc, int col_off)
{
  __shared__ float As[16][68];   // [k][m], pad 68 keeps float4 alignment
  __shared__ float Ws[16][68];   // [k][n]
  const int m0 = blockIdx.y << 6, n0 = blockIdx.x << 6;
  const int t  = threadIdx.x;
  const int tx = t & 15, ty = t >> 4;
  const int lrow = t >> 2, lk = (t & 3) << 2;
  const float* Ap = A + (size_t)(m0 + lrow) * K + lk;
  const float* Wp = W + (size_t)(n0 + lrow) * K + lk;
  float acc[4][4] = {};
  for (int k0 = 0; k0 < K; k0 += 16) {
    __syncthreads();
    float4 av = *(const float4*)(Ap + k0);
    float4 wv = *(const float4*)(Wp + k0);
    As[lk+0][lrow]=av.x; As[lk+1][lrow]=av.y; As[lk+2][lrow]=av.z; As[lk+3][lrow]=av.w;
    Ws[lk+0][lrow]=wv.x; Ws[lk+1][lrow]=wv.y; Ws[lk+2][lrow]=wv.z; Ws[lk+3][lrow]=wv.w;
    __syncthreads();
#pragma unroll
    for (int kk = 0; kk < 16; ++kk) {
      float4 a = *(const float4*)&As[kk][ty<<2];
      float4 w = *(const float4*)&Ws[kk][tx<<2];
      float ar[4] = {a.x,a.y,a.z,a.w};
      float wr[4] = {w.x,w.y,w.z,w.w};
#pragma unroll
      for (int i=0;i<4;++i)
#pragma unroll
        for (int j=0;j<4;++j)
          acc[i][j] = fmaf(ar[i], wr[j], acc[i][j]);
    }
  }
#pragma unroll
  for (int i=0;i<4;++i) {
    *(float4*)(C + (size_t)(m0 + (ty<<2) + i)*ldc + col_off + n0 + (tx<<2)) =
      make_float4(acc[i][0],acc[i][1],acc[i][2],acc[i][3]);
  }
}

// ---------------- RoPE in place on the QKV buffer ----------------
// Y: [M_][3072]; cols 0..2047 = q (32 heads), 2048..2559 = k (8 heads), v untouched.
__global__ void rope_kernel(float* __restrict__ Y, const int* __restrict__ pos_ids)
{
  int idx = blockIdx.x * blockDim.x + threadIdx.x;      // pair index
  const int npairs = M_ * 40 * 32;                      // 40 roped heads (32 q + 8 k)
  if (idx >= npairs) return;
  int d    = idx & 31;
  int hr   = idx >> 5;
  int head = hr % 40;                                   // 0..31 q, 32..39 k
  int m    = hr / 40;                                   // row in [0,2048)
  float* row = Y + (size_t)m * QKVN_;
  int col = head * 64 + d;                              // head*64: q cols 0.., k cols 2048..
  float x0 = row[col], x1 = row[col + 32];
  float p = (float)(pos_ids[m] + 2);                    // position_ids + LCK
  float inv = 1.0f / powf(10000.0f, (float)(2*d) * (1.0f/64.0f));
  float f = p * inv;
  float c, s;
  sincosf(f, &s, &c);
  row[col]      = x0 * c - x1 * s;
  row[col + 32] = x1 * c + x0 * s;
}

// ---------------- Flash attention, fp32 ----------------
// block = (qt, h, b), 256 threads, 64 q-rows per block; k-tiles of 64 over cache_k[0]
// (causal), then 2 tail keys (cache_k[1][...,qpos,:], fresh k[...,qpos,:]) joined into
// the same online softmax.
__global__ __launch_bounds__(256) void attn_kernel(
    const float* __restrict__ Y,        // [M_][3072] qkv, rope applied
    const float* __restrict__ cache_k,  // [2][B][H][Q][64]
    const float* __restrict__ cache_v,
    float* __restrict__ AO)             // [M_][2048]
{
  extern __shared__ float smem[];
  float (*Qs)[68] = (float (*)[68])smem;   // Qs[d][i], pre-scaled by 1/8
  float (*Ks)[68] = Qs + 64;               // Ks[d][j]
  float (*Vs)[68] = Ks + 64;               // Vs[j][d]
  float (*Ps)[68] = Vs + 64;               // Ps[i][j]
  float* m_run   = (float*)(Ps + 64);
  float* l_run   = m_run + 64;
  float* alpha_s = l_run + 64;
  float (*red)[4]  = (float (*)[4])(alpha_s + 64);
  float (*red2)[4] = red + 64;

  const int qt = blockIdx.x, h = blockIdx.y, b = blockIdx.z;
  const int t  = threadIdx.x;
  const int tx = t & 15, ty = t >> 4;
  const int li = t >> 2, lseg = t & 3, ld0 = lseg << 4;

  // load Q tile (scaled)
  {
    const float* qp = Y + (size_t)(b*Q_ + (qt<<6) + li)*QKVN_ + h*HD_ + ld0;
#pragma unroll
    for (int x = 0; x < 16; x += 4) {
      float4 v = *(const float4*)(qp + x);
      Qs[ld0+x+0][li] = v.x * SCALE_;
      Qs[ld0+x+1][li] = v.y * SCALE_;
      Qs[ld0+x+2][li] = v.z * SCALE_;
      Qs[ld0+x+3][li] = v.w * SCALE_;
    }
  }
  if (t < 64) { m_run[t] = -3.0e38f; l_run[t] = 0.f; }

  float acc[4][4] = {};
  const float* k0b = cache_k + (size_t)(b*H_ + h)*Q_*HD_;
  const float* v0b = cache_v + (size_t)(b*H_ + h)*Q_*HD_;

  for (int kt = 0; kt <= qt; ++kt) {
    __syncthreads();
    { // stage K (transposed) and V tiles
      const float* kp = k0b + (size_t)((kt<<6) + li)*HD_ + ld0;
      const float* vp = v0b + (size_t)((kt<<6) + li)*HD_ + ld0;
#pragma unroll
      for (int x = 0; x < 16; x += 4) {
        float4 kv = *(const float4*)(kp + x);
        Ks[ld0+x+0][li] = kv.x; Ks[ld0+x+1][li] = kv.y;
        Ks[ld0+x+2][li] = kv.z; Ks[ld0+x+3][li] = kv.w;
        *(float4*)&Vs[li][ld0+x] = *(const float4*)(vp + x);
      }
    }
    __syncthreads();
    // S = (Q*scale) @ K^T, 4x4 per thread
    float s[4][4] = {};
#pragma unroll 8
    for (int d = 0; d < 64; ++d) {
      float4 a = *(const float4*)&Qs[d][ty<<2];
      float4 w = *(const float4*)&Ks[d][tx<<2];
      float ar[4]={a.x,a.y,a.z,a.w}, wr[4]={w.x,w.y,w.z,w.w};
#pragma unroll
      for (int i=0;i<4;++i)
#pragma unroll
        for (int j=0;j<4;++j)
          s[i][j] = fmaf(ar[i], wr[j], s[i][j]);
    }
    if (kt == qt) { // causal mask on the diagonal tile
#pragma unroll
      for (int i=0;i<4;++i)
#pragma unroll
        for (int j=0;j<4;++j)
          if (((tx<<2)+j) > ((ty<<2)+i)) s[i][j] = -3.0e38f;
    }
#pragma unroll
    for (int i=0;i<4;++i)
      *(float4*)&Ps[(ty<<2)+i][tx<<2] = make_float4(s[i][0],s[i][1],s[i][2],s[i][3]);
    __syncthreads();
    // online softmax: 4 threads per row, 16 cols each
    float mp = -3.0e38f;
#pragma unroll
    for (int jj=0;jj<16;++jj) mp = fmaxf(mp, Ps[li][ld0+jj]);
    red[li][lseg] = mp;
    __syncthreads();
    float mtile = fmaxf(fmaxf(red[li][0],red[li][1]), fmaxf(red[li][2],red[li][3]));
    float mold = m_run[li];
    float mnew = fmaxf(mold, mtile);
    float sp = 0.f;
#pragma unroll
    for (int jj=0;jj<16;++jj) {
      float p = __expf(Ps[li][ld0+jj] - mnew);
      Ps[li][ld0+jj] = p;
      sp += p;
    }
    red2[li][lseg] = sp;
    __syncthreads();
    if (lseg == 0) {
      float al = __expf(mold - mnew);
      l_run[li] = l_run[li]*al + red2[li][0]+red2[li][1]+red2[li][2]+red2[li][3];
      m_run[li] = mnew;
      alpha_s[li] = al;
    }
    __syncthreads();
    // rescale accumulators, then O += P @ V
    float alv[4];
#pragma unroll
    for (int i=0;i<4;++i) alv[i] = alpha_s[(ty<<2)+i];
#pragma unroll
    for (int i=0;i<4;++i)
#pragma unroll
      for (int j=0;j<4;++j) acc[i][j] *= alv[i];
#pragma unroll 4
    for (int j=0;j<64;++j) {
      float4 v = *(const float4*)&Vs[j][tx<<2];
      float vr[4]={v.x,v.y,v.z,v.w};
      float pr[4];
#pragma unroll
      for (int i=0;i<4;++i) pr[i] = Ps[(ty<<2)+i][j];
#pragma unroll
      for (int i=0;i<4;++i)
#pragma unroll
        for (int jj=0;jj<4;++jj)
          acc[i][jj] = fmaf(pr[i], vr[jj], acc[i][jj]);
    }
  }
  __syncthreads();
  // tail keys: e1 = q . cache_k[1][b,h,qpos,:], e2 = q . k_fresh[b,h/4,qpos,:]
  {
    const int qpos = (qt<<6) + li;
    const float* k1p = cache_k + ((size_t)((B_ + b)*H_ + h)*Q_ + qpos)*HD_ + ld0;
    const float* kfp = Y + (size_t)(b*Q_ + qpos)*QKVN_ + H_*HD_ + (h/NREP_)*HD_ + ld0;
    float e1p = 0.f, e2p = 0.f;
#pragma unroll
    for (int x=0;x<16;++x) {
      float qv = Qs[ld0+x][li];
      e1p = fmaf(qv, k1p[x], e1p);
      e2p = fmaf(qv, kfp[x], e2p);
    }
    red[li][lseg]  = e1p;
    red2[li][lseg] = e2p;
  }
  __syncthreads();
#pragma unroll
  for (int ii=0; ii<4; ++ii) {
    const int i = (ty<<2) + ii;
    const int qpos = (qt<<6) + i;
    float e1 = red[i][0]+red[i][1]+red[i][2]+red[i][3];
    float e2 = red2[i][0]+red2[i][1]+red2[i][2]+red2[i][3];
    float mold = m_run[i];
    float mnew = fmaxf(mold, fmaxf(e1, e2));
    float al = __expf(mold - mnew);
    float w1 = __expf(e1 - mnew);
    float w2 = __expf(e2 - mnew);
    float linv = 1.f / (l_run[i]*al + w1 + w2);
    const float4 v1 = *(const float4*)(cache_v + ((size_t)((B_ + b)*H_ + h)*Q_ + qpos)*HD_ + (tx<<2));
    const float4 vf = *(const float4*)(Y + (size_t)(b*Q_ + qpos)*QKVN_ + (H_*HD_ + KVH_*HD_) + (h/NREP_)*HD_ + (tx<<2));
    float4 o;
    o.x = (acc[ii][0]*al + w1*v1.x + w2*vf.x) * linv;
    o.y = (acc[ii][1]*al + w1*v1.y + w2*vf.y) * linv;
    o.z = (acc[ii][2]*al + w1*v1.z + w2*vf.z) * linv;
    o.w = (acc[ii][3]*al + w1*v1.w + w2*vf.w) * linv;
    *(float4*)(AO + (size_t)(b*Q_ + qpos)*AOW_ + h*HD_ + (tx<<2)) = o;
  }
}

extern "C" void kernel_launch(void* const* d_in, const int* in_sizes, int n_in,
                              void* d_out, int out_size, void* d_ws, size_t ws_size,
                              hipStream_t stream) {
  const float* hidden  = (const float*)d_in[0];
  const float* Wq      = (const float*)d_in[1];
  const float* Wk      = (const float*)d_in[2];
  const float* Wv      = (const float*)d_in[3];
  const float* Wo      = (const float*)d_in[4];   // [HS][H*HD]
  const float* cache_k = (const float*)d_in[5];
  const float* cache_v = (const float*)d_in[6];
  const int*   pos_ids = (const int*)d_in[8];
  float* out = (float*)d_out;

  float* Y  = (float*)d_ws;                 // [2048][3072] qkv
  float* AO = Y + (size_t)M_ * QKVN_;       // [2048][2048] attention output

  // QKV projections
  sgemm_nt<<<dim3(32, 32), 256, 0, stream>>>(hidden, Wq, Y, KIN_, QKVN_, 0);
  sgemm_nt<<<dim3(8, 32),  256, 0, stream>>>(hidden, Wk, Y, KIN_, QKVN_, 2048);
  sgemm_nt<<<dim3(8, 32),  256, 0, stream>>>(hidden, Wv, Y, KIN_, QKVN_, 2560);
  // RoPE on q and k, in place
  rope_kernel<<<dim3((M_*40*32 + 255)/256), 256, 0, stream>>>(Y, pos_ids);
  // attention
  const int attn_smem = (4*64*68 + 3*64 + 2*64*4) * sizeof(float);  // 72448 B
  attn_kernel<<<dim3(16, 32, 2), 256, attn_smem, stream>>>(Y, cache_k, cache_v, AO);
  // output projection
  sgemm_nt<<<dim3(32, 32), 256, 0, stream>>>(AO, Wo, out, AOW_, HS_, 0);
}

// Round 2
// 512.017 us; speedup vs baseline: 2.8076x; 2.8076x over previous
//
#include <hip/hip_runtime.h>
#include <hip/hip_bf16.h>
#include <math.h>

#define B_    2
#define Q_    1024
#define H_    32
#define KVH_  8
#define HD_   64
#define HS_   2048
#define NREP_ 4
#define KIN_  (2*HS_)            // 4096
#define M_    (B_*Q_)            // 2048
#define QKVN_ (H_*HD_ + 2*KVH_*HD_)  // 3072
#define AOW_  (H_*HD_)           // 2048
#define SCALE_ 0.125f            // 1/sqrt(64)

typedef __attribute__((ext_vector_type(8))) short bf16x8;
typedef __attribute__((ext_vector_type(4))) float f32x4;

// ---------------- fp32 -> bf16 cast (vectorized, 8 elems/thread) ----------------
__global__ __launch_bounds__(256) void cast_f32_bf16(
    const float* __restrict__ src, __hip_bfloat16* __restrict__ dst, long n)
{
  long i = ((long)blockIdx.x * blockDim.x + threadIdx.x) * 8;
  if (i >= n) return;
  float4 a = *(const float4*)(src + i);
  float4 b = *(const float4*)(src + i + 4);
  __hip_bfloat16 o[8] = {
    __float2bfloat16(a.x), __float2bfloat16(a.y), __float2bfloat16(a.z), __float2bfloat16(a.w),
    __float2bfloat16(b.x), __float2bfloat16(b.y), __float2bfloat16(b.z), __float2bfloat16(b.w)};
  *(float4*)(dst + i) = *(const float4*)o;   // 16B store of 8 bf16
}

// ---------------- bf16 NT MFMA GEMM: C[m][n] = sum_k A[m][k]*W[n][k] ----------------
// 128x128 tile, BK=32, 256 threads = 4 waves (2x2), 64x64 per wave as 4x4 16x16 frags.
// A: [M][K] bf16 row-major, W: [N][K] bf16 row-major, C: [M][ldc] fp32.
__global__ __launch_bounds__(256) void gemm_bf16_nt(
    const __hip_bfloat16* __restrict__ A, const __hip_bfloat16* __restrict__ W,
    float* __restrict__ C, int K, int ldc)
{
  __shared__ __hip_bfloat16 As[128 * 32];
  __shared__ __hip_bfloat16 Bs[128 * 32];
  const int m0 = blockIdx.y << 7, n0 = blockIdx.x << 7;
  const int t = threadIdx.x;
  const int wave = t >> 6, lane = t & 63;
  const int wr = wave >> 1, wc = wave & 1;

  f32x4 acc[4][4] = {};

  const int lrow4 = lane >> 2;          // 0..15
  const int lk8   = (lane & 3) * 8;     // k element offset for staging
  const int fr    = lane & 15;          // fragment row/col within 16
  const int fk    = (lane >> 4) * 8;    // fragment k element offset

  for (int k0 = 0; k0 < K; k0 += 32) {
    __syncthreads();
#pragma unroll
    for (int p = 0; p < 2; ++p) {
      // wave-uniform LDS base; lanes land at base + lane*16 (HW rule)
      int rbase = p * 64 + wave * 16;
      const __hip_bfloat16* srcA = A + (size_t)(m0 + rbase + lrow4) * K + k0 + lk8;
      const __hip_bfloat16* srcB = W + (size_t)(n0 + rbase + lrow4) * K + k0 + lk8;
      __builtin_amdgcn_global_load_lds(
          (const __attribute__((address_space(1))) void*)srcA,
          (__attribute__((address_space(3))) void*)(As + rbase * 32), 16, 0, 0);
      __builtin_amdgcn_global_load_lds(
          (const __attribute__((address_space(1))) void*)srcB,
          (__attribute__((address_space(3))) void*)(Bs + rbase * 32), 16, 0, 0);
    }
    __syncthreads();

    bf16x8 af[4], bf[4];
#pragma unroll
    for (int i = 0; i < 4; ++i) {
      af[i] = *(const bf16x8*)(As + (wr * 64 + i * 16 + fr) * 32 + fk);
      bf[i] = *(const bf16x8*)(Bs + (wc * 64 + i * 16 + fr) * 32 + fk);
    }
#pragma unroll
    for (int mi = 0; mi < 4; ++mi)
#pragma unroll
      for (int ni = 0; ni < 4; ++ni)
        acc[mi][ni] = __builtin_amdgcn_mfma_f32_16x16x32_bf16(af[mi], bf[ni], acc[mi][ni], 0, 0, 0);
  }

  // C/D layout: col = lane&15, row = (lane>>4)*4 + reg
  const int crow = (lane >> 4) * 2;  // *4 /2... see below
#pragma unroll
  for (int mi = 0; mi < 4; ++mi) {
    int rbase = m0 + wr * 64 + mi * 16 + (lane >> 4) * 4;
#pragma unroll
    for (int ni = 0; ni < 4; ++ni) {
      int col = n0 + wc * 64 + ni * 16 + (lane & 15);
#pragma unroll
      for (int r = 0; r < 4; ++r)
        C[(size_t)(rbase + r) * ldc + col] = acc[mi][ni][r];
    }
  }
  (void)crow;
}

// ---------------- RoPE in place on the QKV buffer ----------------
__global__ void rope_kernel(float* __restrict__ Y, const int* __restrict__ pos_ids)
{
  int idx = blockIdx.x * blockDim.x + threadIdx.x;      // pair index
  const int npairs = M_ * 40 * 32;                      // 40 roped heads (32 q + 8 k)
  if (idx >= npairs) return;
  int d    = idx & 31;
  int hr   = idx >> 5;
  int head = hr % 40;
  int m    = hr / 40;
  float* row = Y + (size_t)m * QKVN_;
  int col = head * 64 + d;
  float x0 = row[col], x1 = row[col + 32];
  float p = (float)(pos_ids[m] + 2);
  float inv = 1.0f / powf(10000.0f, (float)(2*d) * (1.0f/64.0f));
  float f = p * inv;
  float c, s;
  sincosf(f, &s, &c);
  row[col]      = x0 * c - x1 * s;
  row[col + 32] = x1 * c + x0 * s;
}

// ---------------- Flash attention, fp32 ----------------
__global__ __launch_bounds__(256) void attn_kernel(
    const float* __restrict__ Y,        // [M_][3072] qkv, rope applied
    const float* __restrict__ cache_k,  // [2][B][H][Q][64]
    const float* __restrict__ cache_v,
    float* __restrict__ AO)             // [M_][2048]
{
  extern __shared__ float smem[];
  float (*Qs)[68] = (float (*)[68])smem;
  float (*Ks)[68] = Qs + 64;
  float (*Vs)[68] = Ks + 64;
  float (*Ps)[68] = Vs + 64;
  float* m_run   = (float*)(Ps + 64);
  float* l_run   = m_run + 64;
  float* alpha_s = l_run + 64;
  float (*red)[4]  = (float (*)[4])(alpha_s + 64);
  float (*red2)[4] = red + 64;

  const int qt = blockIdx.x, h = blockIdx.y, b = blockIdx.z;
  const int t  = threadIdx.x;
  const int tx = t & 15, ty = t >> 4;
  const int li = t >> 2, lseg = t & 3, ld0 = lseg << 4;

  {
    const float* qp = Y + (size_t)(b*Q_ + (qt<<6) + li)*QKVN_ + h*HD_ + ld0;
#pragma unroll
    for (int x = 0; x < 16; x += 4) {
      float4 v = *(const float4*)(qp + x);
      Qs[ld0+x+0][li] = v.x * SCALE_;
      Qs[ld0+x+1][li] = v.y * SCALE_;
      Qs[ld0+x+2][li] = v.z * SCALE_;
      Qs[ld0+x+3][li] = v.w * SCALE_;
    }
  }
  if (t < 64) { m_run[t] = -3.0e38f; l_run[t] = 0.f; }

  float acc[4][4] = {};
  const float* k0b = cache_k + (size_t)(b*H_ + h)*Q_*HD_;
  const float* v0b = cache_v + (size_t)(b*H_ + h)*Q_*HD_;

  for (int kt = 0; kt <= qt; ++kt) {
    __syncthreads();
    {
      const float* kp = k0b + (size_t)((kt<<6) + li)*HD_ + ld0;
      const float* vp = v0b + (size_t)((kt<<6) + li)*HD_ + ld0;
#pragma unroll
      for (int x = 0; x < 16; x += 4) {
        float4 kv = *(const float4*)(kp + x);
        Ks[ld0+x+0][li] = kv.x; Ks[ld0+x+1][li] = kv.y;
        Ks[ld0+x+2][li] = kv.z; Ks[ld0+x+3][li] = kv.w;
        *(float4*)&Vs[li][ld0+x] = *(const float4*)(vp + x);
      }
    }
    __syncthreads();
    float s[4][4] = {};
#pragma unroll 8
    for (int d = 0; d < 64; ++d) {
      float4 a = *(const float4*)&Qs[d][ty<<2];
      float4 w = *(const float4*)&Ks[d][tx<<2];
      float ar[4]={a.x,a.y,a.z,a.w}, wr[4]={w.x,w.y,w.z,w.w};
#pragma unroll
      for (int i=0;i<4;++i)
#pragma unroll
        for (int j=0;j<4;++j)
          s[i][j] = fmaf(ar[i], wr[j], s[i][j]);
    }
    if (kt == qt) {
#pragma unroll
      for (int i=0;i<4;++i)
#pragma unroll
        for (int j=0;j<4;++j)
          if (((tx<<2)+j) > ((ty<<2)+i)) s[i][j] = -3.0e38f;
    }
#pragma unroll
    for (int i=0;i<4;++i)
      *(float4*)&Ps[(ty<<2)+i][tx<<2] = make_float4(s[i][0],s[i][1],s[i][2],s[i][3]);
    __syncthreads();
    float mp = -3.0e38f;
#pragma unroll
    for (int jj=0;jj<16;++jj) mp = fmaxf(mp, Ps[li][ld0+jj]);
    red[li][lseg] = mp;
    __syncthreads();
    float mtile = fmaxf(fmaxf(red[li][0],red[li][1]), fmaxf(red[li][2],red[li][3]));
    float mold = m_run[li];
    float mnew = fmaxf(mold, mtile);
    float sp = 0.f;
#pragma unroll
    for (int jj=0;jj<16;++jj) {
      float p = __expf(Ps[li][ld0+jj] - mnew);
      Ps[li][ld0+jj] = p;
      sp += p;
    }
    red2[li][lseg] = sp;
    __syncthreads();
    if (lseg == 0) {
      float al = __expf(mold - mnew);
      l_run[li] = l_run[li]*al + red2[li][0]+red2[li][1]+red2[li][2]+red2[li][3];
      m_run[li] = mnew;
      alpha_s[li] = al;
    }
    __syncthreads();
    float alv[4];
#pragma unroll
    for (int i=0;i<4;++i) alv[i] = alpha_s[(ty<<2)+i];
#pragma unroll
    for (int i=0;i<4;++i)
#pragma unroll
      for (int j=0;j<4;++j) acc[i][j] *= alv[i];
#pragma unroll 4
    for (int j=0;j<64;++j) {
      float4 v = *(const float4*)&Vs[j][tx<<2];
      float vr[4]={v.x,v.y,v.z,v.w};
      float pr[4];
#pragma unroll
      for (int i=0;i<4;++i) pr[i] = Ps[(ty<<2)+i][j];
#pragma unroll
      for (int i=0;i<4;++i)
#pragma unroll
        for (int jj=0;jj<4;++jj)
          acc[i][jj] = fmaf(pr[i], vr[jj], acc[i][jj]);
    }
  }
  __syncthreads();
  {
    const int qpos = (qt<<6) + li;
    const float* k1p = cache_k + ((size_t)((B_ + b)*H_ + h)*Q_ + qpos)*HD_ + ld0;
    const float* kfp = Y + (size_t)(b*Q_ + qpos)*QKVN_ + H_*HD_ + (h/NREP_)*HD_ + ld0;
    float e1p = 0.f, e2p = 0.f;
#pragma unroll
    for (int x=0;x<16;++x) {
      float qv = Qs[ld0+x][li];
      e1p = fmaf(qv, k1p[x], e1p);
      e2p = fmaf(qv, kfp[x], e2p);
    }
    red[li][lseg]  = e1p;
    red2[li][lseg] = e2p;
  }
  __syncthreads();
#pragma unroll
  for (int ii=0; ii<4; ++ii) {
    const int i = (ty<<2) + ii;
    const int qpos = (qt<<6) + i;
    float e1 = red[i][0]+red[i][1]+red[i][2]+red[i][3];
    float e2 = red2[i][0]+red2[i][1]+red2[i][2]+red2[i][3];
    float mold = m_run[i];
    float mnew = fmaxf(mold, fmaxf(e1, e2));
    float al = __expf(mold - mnew);
    float w1 = __expf(e1 - mnew);
    float w2 = __expf(e2 - mnew);
    float linv = 1.f / (l_run[i]*al + w1 + w2);
    const float4 v1 = *(const float4*)(cache_v + ((size_t)((B_ + b)*H_ + h)*Q_ + qpos)*HD_ + (tx<<2));
    const float4 vf = *(const float4*)(Y + (size_t)(b*Q_ + qpos)*QKVN_ + (H_*HD_ + KVH_*HD_) + (h/NREP_)*HD_ + (tx<<2));
    float4 o;
    o.x = (acc[ii][0]*al + w1*v1.x + w2*vf.x) * linv;
    o.y = (acc[ii][1]*al + w1*v1.y + w2*vf.y) * linv;
    o.z = (acc[ii][2]*al + w1*v1.z + w2*vf.z) * linv;
    o.w = (acc[ii][3]*al + w1*v1.w + w2*vf.w) * linv;
    *(float4*)(AO + (size_t)(b*Q_ + qpos)*AOW_ + h*HD_ + (tx<<2)) = o;
  }
}

extern "C" void kernel_launch(void* const* d_in, const int* in_sizes, int n_in,
                              void* d_out, int out_size, void* d_ws, size_t ws_size,
                              hipStream_t stream) {
  const float* hidden  = (const float*)d_in[0];
  const float* Wq      = (const float*)d_in[1];
  const float* Wk      = (const float*)d_in[2];
  const float* Wv      = (const float*)d_in[3];
  const float* Wo      = (const float*)d_in[4];   // [HS][H*HD]
  const float* cache_k = (const float*)d_in[5];
  const float* cache_v = (const float*)d_in[6];
  const int*   pos_ids = (const int*)d_in[8];
  float* out = (float*)d_out;

  // workspace layout
  char* ws = (char*)d_ws;
  float* Y  = (float*)ws;                                  // [2048][3072] fp32
  ws += (size_t)M_ * QKVN_ * 4;
  float* AO = (float*)ws;                                  // [2048][2048] fp32
  ws += (size_t)M_ * AOW_ * 4;
  __hip_bfloat16* Xb  = (__hip_bfloat16*)ws;               // [2048][4096] bf16
  ws += (size_t)M_ * KIN_ * 2;
  __hip_bfloat16* Wb  = (__hip_bfloat16*)ws;               // [3072][4096] bf16
  ws += (size_t)QKVN_ * KIN_ * 2;
  __hip_bfloat16* Wob = (__hip_bfloat16*)ws;               // [2048][2048] bf16
  __hip_bfloat16* AOb = Xb;                                // alias: Xb dead after QKV GEMM

  // casts
  {
    long n;
    n = (long)M_ * KIN_;
    cast_f32_bf16<<<dim3((n/8 + 255)/256), 256, 0, stream>>>(hidden, Xb, n);
    n = (long)H_*HD_*KIN_;
    cast_f32_bf16<<<dim3((n/8 + 255)/256), 256, 0, stream>>>(Wq, Wb, n);
    n = (long)KVH_*HD_*KIN_;
    cast_f32_bf16<<<dim3((n/8 + 255)/256), 256, 0, stream>>>(Wk, Wb + (size_t)2048*KIN_, n);
    cast_f32_bf16<<<dim3((n/8 + 255)/256), 256, 0, stream>>>(Wv, Wb + (size_t)2560*KIN_, n);
    n = (long)HS_ * AOW_;
    cast_f32_bf16<<<dim3((n/8 + 255)/256), 256, 0, stream>>>(Wo, Wob, n);
  }

  // QKV projection: [2048][4096] x [3072][4096]^T -> Y [2048][3072]
  gemm_bf16_nt<<<dim3(QKVN_/128, M_/128), 256, 0, stream>>>(Xb, Wb, Y, KIN_, QKVN_);
  // RoPE on q and k, in place
  rope_kernel<<<dim3((M_*40*32 + 255)/256), 256, 0, stream>>>(Y, pos_ids);
  // attention
  const int attn_smem = (4*64*68 + 3*64 + 2*64*4) * sizeof(float);  // 72448 B
  attn_kernel<<<dim3(16, 32, 2), 256, attn_smem, stream>>>(Y, cache_k, cache_v, AO);
  // cast AO -> bf16, then output projection
  {
    long n = (long)M_ * AOW_;
    cast_f32_bf16<<<dim3((n/8 + 255)/256), 256, 0, stream>>>(AO, AOb, n);
  }
  gemm_bf16_nt<<<dim3(HS_/128, M_/128), 256, 0, stream>>>(AOb, Wob, out, AOW_, HS_);
}

// Round 3
// 282.886 us; speedup vs baseline: 5.0817x; 1.8100x over previous
//
#include <hip/hip_runtime.h>
#include <hip/hip_bf16.h>
#include <math.h>

#define B_    2
#define Q_    1024
#define H_    32
#define KVH_  8
#define HD_   64
#define HS_   2048
#define NREP_ 4
#define KIN_  (2*HS_)            // 4096
#define M_    (B_*Q_)            // 2048
#define QKVN_ (H_*HD_ + 2*KVH_*HD_)  // 3072
#define AOW_  (H_*HD_)           // 2048
#define SCALE_ 0.125f            // 1/sqrt(64)

typedef __attribute__((ext_vector_type(8))) short bf16x8;
typedef __attribute__((ext_vector_type(4))) float f32x4;

static __device__ __forceinline__ unsigned short f2b(float f) {
  union { float f; unsigned int u; } c; c.f = f;
  unsigned int r = (c.u + 0x7fffu + ((c.u >> 16) & 1u)) >> 16;
  return (unsigned short)r;
}
static __device__ __forceinline__ float b2f(short s) {
  union { unsigned int u; float f; } c;
  c.u = ((unsigned int)(unsigned short)s) << 16;
  return c.f;
}
static __device__ __forceinline__ unsigned long long pack4s(float4 v, float sc) {
  return (unsigned long long)f2b(v.x*sc) |
         ((unsigned long long)f2b(v.y*sc) << 16) |
         ((unsigned long long)f2b(v.z*sc) << 32) |
         ((unsigned long long)f2b(v.w*sc) << 48);
}

// ---------------- fp32 -> bf16 cast (vectorized, 8 elems/thread) ----------------
__global__ __launch_bounds__(256) void cast_f32_bf16(
    const float* __restrict__ src, __hip_bfloat16* __restrict__ dst, long n)
{
  long i = ((long)blockIdx.x * blockDim.x + threadIdx.x) * 8;
  if (i >= n) return;
  float4 a = *(const float4*)(src + i);
  float4 b = *(const float4*)(src + i + 4);
  unsigned long long w0 = pack4s(a, 1.f), w1 = pack4s(b, 1.f);
  unsigned long long o[2] = {w0, w1};
  *(float4*)(dst + i) = *(const float4*)o;
}

// ---------------- bf16 NT MFMA GEMM (unchanged from round 2, passing) ----------------
__global__ __launch_bounds__(256) void gemm_bf16_nt(
    const __hip_bfloat16* __restrict__ A, const __hip_bfloat16* __restrict__ W,
    float* __restrict__ C, int K, int ldc)
{
  __shared__ __hip_bfloat16 As[128 * 32];
  __shared__ __hip_bfloat16 Bs[128 * 32];
  const int m0 = blockIdx.y << 7, n0 = blockIdx.x << 7;
  const int t = threadIdx.x;
  const int wave = t >> 6, lane = t & 63;
  const int wr = wave >> 1, wc = wave & 1;

  f32x4 acc[4][4] = {};

  const int lrow4 = lane >> 2;
  const int lk8   = (lane & 3) * 8;
  const int fr    = lane & 15;
  const int fk    = (lane >> 4) * 8;

  for (int k0 = 0; k0 < K; k0 += 32) {
    __syncthreads();
#pragma unroll
    for (int p = 0; p < 2; ++p) {
      int rbase = p * 64 + wave * 16;
      const __hip_bfloat16* srcA = A + (size_t)(m0 + rbase + lrow4) * K + k0 + lk8;
      const __hip_bfloat16* srcB = W + (size_t)(n0 + rbase + lrow4) * K + k0 + lk8;
      __builtin_amdgcn_global_load_lds(
          (const __attribute__((address_space(1))) void*)srcA,
          (__attribute__((address_space(3))) void*)(As + rbase * 32), 16, 0, 0);
      __builtin_amdgcn_global_load_lds(
          (const __attribute__((address_space(1))) void*)srcB,
          (__attribute__((address_space(3))) void*)(Bs + rbase * 32), 16, 0, 0);
    }
    __syncthreads();

    bf16x8 af[4], bfr[4];
#pragma unroll
    for (int i = 0; i < 4; ++i) {
      af[i]  = *(const bf16x8*)(As + (wr * 64 + i * 16 + fr) * 32 + fk);
      bfr[i] = *(const bf16x8*)(Bs + (wc * 64 + i * 16 + fr) * 32 + fk);
    }
#pragma unroll
    for (int mi = 0; mi < 4; ++mi)
#pragma unroll
      for (int ni = 0; ni < 4; ++ni)
        acc[mi][ni] = __builtin_amdgcn_mfma_f32_16x16x32_bf16(af[mi], bfr[ni], acc[mi][ni], 0, 0, 0);
  }

#pragma unroll
  for (int mi = 0; mi < 4; ++mi) {
    int rbase = m0 + wr * 64 + mi * 16 + (lane >> 4) * 4;
#pragma unroll
    for (int ni = 0; ni < 4; ++ni) {
      int col = n0 + wc * 64 + ni * 16 + (lane & 15);
#pragma unroll
      for (int r = 0; r < 4; ++r)
        C[(size_t)(rbase + r) * ldc + col] = acc[mi][ni][r];
    }
  }
}

// ---------------- RoPE in place on the QKV buffer ----------------
__global__ void rope_kernel(float* __restrict__ Y, const int* __restrict__ pos_ids)
{
  int idx = blockIdx.x * blockDim.x + threadIdx.x;
  const int npairs = M_ * 40 * 32;
  if (idx >= npairs) return;
  int d    = idx & 31;
  int hr   = idx >> 5;
  int head = hr % 40;
  int m    = hr / 40;
  float* row = Y + (size_t)m * QKVN_;
  int col = head * 64 + d;
  float x0 = row[col], x1 = row[col + 32];
  float p = (float)(pos_ids[m] + 2);
  float inv = exp2f(-0.4152410118609203f * (float)d);   // 10000^(-2d/64)
  float f = p * inv;
  float c, s;
  sincosf(f, &s, &c);
  row[col]      = x0 * c - x1 * s;
  row[col + 32] = x1 * c + x0 * s;
}

// ---------------- MFMA flash attention, bf16 ----------------
// Block: 256 threads = 4 waves; QBLK=64 (16 q-rows/wave), KVBLK=64.
// Qs/Ks: [row][d] bf16, d-block swizzle kb^=(row&7).
// Vt:    [d][k]  bf16, k-block swizzle kb^=((d^(d>>3))&7).
// Ps:    wave-private [16][64], swizzle kb^=(row&7).
__global__ __launch_bounds__(256) void attn_mfma(
    const float* __restrict__ Y,        // [M_][3072], rope applied
    const float* __restrict__ cache_k,  // [2][B][H][Q][64]
    const float* __restrict__ cache_v,
    unsigned short* __restrict__ AOb)   // [M_][2048] bf16 out
{
  __shared__ unsigned short Qs[64*64];
  __shared__ unsigned short Ks[64*64];
  __shared__ unsigned short Vt[64*64];
  __shared__ unsigned short Ps[64*64];

  const int qt = blockIdx.x, h = blockIdx.y, b = blockIdx.z;
  const int t = threadIdx.x;
  const int wave = t >> 6, lane = t & 63;
  const int li = t >> 2, lseg = t & 3;     // staging: row 0..63, d-segment
  const int g = lane >> 4, sub = lane & 15;
  const int wq0 = wave * 16;

  // ---- stage Q tile (scaled bf16, swizzled) ----
  {
    const float* qp = Y + (size_t)(b*Q_ + (qt<<6) + li)*QKVN_ + h*HD_ + lseg*16;
#pragma unroll
    for (int c = 0; c < 4; ++c) {
      float4 v = *(const float4*)(qp + 4*c);
      int k0 = lseg*16 + 4*c;
      int dst = li*64 + ((((k0>>3) ^ (li&7)))<<3) + (k0&7);
      *(unsigned long long*)&Qs[dst] = pack4s(v, SCALE_);
    }
  }
  __syncthreads();

  // ---- hoist Q fragments (A-operand: row=sub, k=(g+4kk)*8) ----
  bf16x8 qa[2];
#pragma unroll
  for (int kk = 0; kk < 2; ++kk) {
    int row = wq0 + sub;
    int kb = g + 4*kk;
    qa[kk] = *(const bf16x8*)&Qs[row*64 + ((kb ^ (row&7))<<3)];
  }

  float m_run[4] = {-3e38f,-3e38f,-3e38f,-3e38f};
  float l_run[4] = {0.f,0.f,0.f,0.f};
  f32x4 acc_o[4] = {};

  const float* k0b = cache_k + (size_t)(b*H_ + h)*Q_*HD_;
  const float* v0b = cache_v + (size_t)(b*H_ + h)*Q_*HD_;

  for (int kt = 0; kt <= qt; ++kt) {
    __syncthreads();
    { // stage K tile [k][d] swizzled
      const float* kp = k0b + (size_t)((kt<<6) + li)*HD_ + lseg*16;
#pragma unroll
      for (int c = 0; c < 4; ++c) {
        float4 v = *(const float4*)(kp + 4*c);
        int k0 = lseg*16 + 4*c;
        int dst = li*64 + ((((k0>>3) ^ (li&7)))<<3) + (k0&7);
        *(unsigned long long*)&Ks[dst] = pack4s(v, 1.f);
      }
      // stage V transposed [d][k] swizzled
      const float* vp = v0b + (size_t)((kt<<6) + li)*HD_ + lseg*16;
#pragma unroll
      for (int c = 0; c < 4; ++c) {
        float4 v = *(const float4*)(vp + 4*c);
        float vv[4] = {v.x, v.y, v.z, v.w};
#pragma unroll
        for (int i = 0; i < 4; ++i) {
          int d = lseg*16 + 4*c + i;
          int gd = (d ^ (d>>3)) & 7;
          Vt[d*64 + (li ^ (gd<<3))] = f2b(vv[i]);
        }
      }
    }
    __syncthreads();

    // ---- S = Q K^T ----
    f32x4 s[4] = {};
#pragma unroll
    for (int kk = 0; kk < 2; ++kk) {
      int kb = g + 4*kk;
#pragma unroll
      for (int cb = 0; cb < 4; ++cb) {
        int krow = cb*16 + sub;
        bf16x8 kf = *(const bf16x8*)&Ks[krow*64 + ((kb ^ (krow&7))<<3)];
        s[cb] = __builtin_amdgcn_mfma_f32_16x16x32_bf16(qa[kk], kf, s[cb], 0, 0, 0);
      }
    }
    if (kt == qt) { // causal mask on diagonal tile
#pragma unroll
      for (int cb = 0; cb < 4; ++cb) {
        int kcol = cb*16 + sub;
#pragma unroll
        for (int r = 0; r < 4; ++r) {
          int qrow = wq0 + 4*g + r;
          if (kcol > qrow) s[cb][r] = -3e38f;
        }
      }
    }

    // ---- online softmax (row-reduce over lane bits 0-3) ----
    float mt[4];
#pragma unroll
    for (int r = 0; r < 4; ++r)
      mt[r] = fmaxf(fmaxf(s[0][r], s[1][r]), fmaxf(s[2][r], s[3][r]));
#pragma unroll
    for (int x = 1; x < 16; x <<= 1)
#pragma unroll
      for (int r = 0; r < 4; ++r)
        mt[r] = fmaxf(mt[r], __shfl_xor(mt[r], x, 64));

    float al[4], sum[4];
#pragma unroll
    for (int r = 0; r < 4; ++r) {
      float mnew = fmaxf(m_run[r], mt[r]);
      al[r] = __expf(m_run[r] - mnew);
      m_run[r] = mnew;
      sum[r] = 0.f;
    }
#pragma unroll
    for (int cb = 0; cb < 4; ++cb) {
      int k0 = cb*16 + sub;
      int kb = k0 >> 3;
#pragma unroll
      for (int r = 0; r < 4; ++r) {
        float p = __expf(s[cb][r] - m_run[r]);
        sum[r] += p;
        int prow = 4*g + r;
        Ps[(wq0 + prow)*64 + ((kb ^ (prow&7))<<3) + (k0&7)] = f2b(p);
      }
    }
#pragma unroll
    for (int x = 1; x < 16; x <<= 1)
#pragma unroll
      for (int r = 0; r < 4; ++r)
        sum[r] += __shfl_xor(sum[r], x, 64);
#pragma unroll
    for (int r = 0; r < 4; ++r)
      l_run[r] = l_run[r]*al[r] + sum[r];

    // ---- rescale O, then O += P V ----
#pragma unroll
    for (int db = 0; db < 4; ++db)
#pragma unroll
      for (int r = 0; r < 4; ++r)
        acc_o[db][r] *= al[r];
#pragma unroll
    for (int kk = 0; kk < 2; ++kk) {
      int kb = g + 4*kk;
      int prow = wq0 + sub;
      bf16x8 pa = *(const bf16x8*)&Ps[prow*64 + ((kb ^ (sub&7))<<3)];
#pragma unroll
      for (int db = 0; db < 4; ++db) {
        int drow = db*16 + sub;
        int gd = (drow ^ (drow>>3)) & 7;
        bf16x8 vf = *(const bf16x8*)&Vt[drow*64 + ((kb ^ gd)<<3)];
        acc_o[db] = __builtin_amdgcn_mfma_f32_16x16x32_bf16(pa, vf, acc_o[db], 0, 0, 0);
      }
    }
  }

  // ---- tail: 2 extra keys (cache_k[1] diag, fresh k diag) ----
  const int qrow_mine = wq0 + sub;
  const int qpos_mine = (qt<<6) + qrow_mine;
  float e1 = 0.f, e2 = 0.f;
  {
    const float* k1p = cache_k + ((size_t)((B_ + b)*H_ + h)*Q_ + qpos_mine)*HD_ + g*16;
    const float* kfp = Y + (size_t)(b*Q_ + qpos_mine)*QKVN_ + H_*HD_ + (h/NREP_)*HD_ + g*16;
    float qv[16];
#pragma unroll
    for (int half = 0; half < 2; ++half) {
      int kb = 2*g + half;
      bf16x8 qq = *(const bf16x8*)&Qs[qrow_mine*64 + ((kb ^ (qrow_mine&7))<<3)];
#pragma unroll
      for (int i = 0; i < 8; ++i) qv[half*8 + i] = b2f(qq[i]);
    }
#pragma unroll
    for (int c = 0; c < 4; ++c) {
      float4 kv1 = *(const float4*)(k1p + 4*c);
      float4 kvf = *(const float4*)(kfp + 4*c);
      e1 += qv[4*c]*kv1.x + qv[4*c+1]*kv1.y + qv[4*c+2]*kv1.z + qv[4*c+3]*kv1.w;
      e2 += qv[4*c]*kvf.x + qv[4*c+1]*kvf.y + qv[4*c+2]*kvf.z + qv[4*c+3]*kvf.w;
    }
  }
  e1 += __shfl_xor(e1, 16, 64); e1 += __shfl_xor(e1, 32, 64);
  e2 += __shfl_xor(e2, 16, 64); e2 += __shfl_xor(e2, 32, 64);

#pragma unroll
  for (int r = 0; r < 4; ++r) {
    int row = 4*g + r;                       // 0..15 within wave
    int src = (lane & 48) | row;
    float e1r = __shfl(e1, src, 64);
    float e2r = __shfl(e2, src, 64);
    float mnew = fmaxf(m_run[r], fmaxf(e1r, e2r));
    float alr = __expf(m_run[r] - mnew);
    float w1  = __expf(e1r - mnew);
    float w2  = __expf(e2r - mnew);
    float linv = 1.f / (l_run[r]*alr + w1 + w2);
    int qpos = (qt<<6) + wq0 + row;
    const float* v1p = cache_v + ((size_t)((B_ + b)*H_ + h)*Q_ + qpos)*HD_;
    const float* vfp = Y + (size_t)(b*Q_ + qpos)*QKVN_ + (H_*HD_ + KVH_*HD_) + (h/NREP_)*HD_;
    unsigned short* op = AOb + (size_t)(b*Q_ + qpos)*AOW_ + h*HD_;
#pragma unroll
    for (int db = 0; db < 4; ++db) {
      int d = db*16 + sub;
      float o = (acc_o[db][r]*alr + w1*v1p[d] + w2*vfp[d]) * linv;
      op[d] = f2b(o);
    }
  }
}

extern "C" void kernel_launch(void* const* d_in, const int* in_sizes, int n_in,
                              void* d_out, int out_size, void* d_ws, size_t ws_size,
                              hipStream_t stream) {
  const float* hidden  = (const float*)d_in[0];
  const float* Wq      = (const float*)d_in[1];
  const float* Wk      = (const float*)d_in[2];
  const float* Wv      = (const float*)d_in[3];
  const float* Wo      = (const float*)d_in[4];   // [HS][H*HD]
  const float* cache_k = (const float*)d_in[5];
  const float* cache_v = (const float*)d_in[6];
  const int*   pos_ids = (const int*)d_in[8];
  float* out = (float*)d_out;

  // workspace layout
  char* ws = (char*)d_ws;
  float* Y = (float*)ws;                                   // [2048][3072] fp32
  ws += (size_t)M_ * QKVN_ * 4;
  __hip_bfloat16* Xb  = (__hip_bfloat16*)ws;               // [2048][4096] bf16
  ws += (size_t)M_ * KIN_ * 2;
  __hip_bfloat16* Wb  = (__hip_bfloat16*)ws;               // [3072][4096] bf16
  ws += (size_t)QKVN_ * KIN_ * 2;
  __hip_bfloat16* Wob = (__hip_bfloat16*)ws;               // [2048][2048] bf16
  __hip_bfloat16* AOb = Xb;                                // Xb dead after QKV GEMM

  {
    long n;
    n = (long)M_ * KIN_;
    cast_f32_bf16<<<dim3((n/8 + 255)/256), 256, 0, stream>>>(hidden, Xb, n);
    n = (long)H_*HD_*KIN_;
    cast_f32_bf16<<<dim3((n/8 + 255)/256), 256, 0, stream>>>(Wq, Wb, n);
    n = (long)KVH_*HD_*KIN_;
    cast_f32_bf16<<<dim3((n/8 + 255)/256), 256, 0, stream>>>(Wk, Wb + (size_t)2048*KIN_, n);
    cast_f32_bf16<<<dim3((n/8 + 255)/256), 256, 0, stream>>>(Wv, Wb + (size_t)2560*KIN_, n);
    n = (long)HS_ * AOW_;
    cast_f32_bf16<<<dim3((n/8 + 255)/256), 256, 0, stream>>>(Wo, Wob, n);
  }

  gemm_bf16_nt<<<dim3(QKVN_/128, M_/128), 256, 0, stream>>>(Xb, Wb, Y, KIN_, QKVN_);
  rope_kernel<<<dim3((M_*40*32 + 255)/256), 256, 0, stream>>>(Y, pos_ids);
  attn_mfma<<<dim3(16, 32, 2), 256, 0, stream>>>(Y, cache_k, cache_v, (unsigned short*)AOb);
  gemm_bf16_nt<<<dim3(HS_/128, M_/128), 256, 0, stream>>>(AOb, Wob, out, AOW_, HS_);
}

// Round 4
// 237.270 us; speedup vs baseline: 6.0587x; 1.1923x over previous
//
#include <hip/hip_runtime.h>
#include <hip/hip_bf16.h>
#include <math.h>

#define B_    2
#define Q_    1024
#define H_    32
#define KVH_  8
#define HD_   64
#define HS_   2048
#define NREP_ 4
#define KIN_  (2*HS_)            // 4096
#define M_    (B_*Q_)            // 2048
#define QKVN_ (H_*HD_ + 2*KVH_*HD_)  // 3072
#define AOW_  (H_*HD_)           // 2048
#define SCALE_ 0.125f            // 1/sqrt(64)

typedef __attribute__((ext_vector_type(8))) short bf16x8;
typedef __attribute__((ext_vector_type(4))) float f32x4;

static __device__ __forceinline__ unsigned short f2b(float f) {
  union { float f; unsigned int u; } c; c.f = f;
  unsigned int r = (c.u + 0x7fffu + ((c.u >> 16) & 1u)) >> 16;
  return (unsigned short)r;
}
static __device__ __forceinline__ float b2f(short s) {
  union { unsigned int u; float f; } c;
  c.u = ((unsigned int)(unsigned short)s) << 16;
  return c.f;
}
static __device__ __forceinline__ unsigned long long pack4s(float4 v, float sc) {
  return (unsigned long long)f2b(v.x*sc) |
         ((unsigned long long)f2b(v.y*sc) << 16) |
         ((unsigned long long)f2b(v.z*sc) << 32) |
         ((unsigned long long)f2b(v.w*sc) << 48);
}

// ---------------- fp32 -> bf16 cast ----------------
__global__ __launch_bounds__(256) void cast_f32_bf16(
    const float* __restrict__ src, __hip_bfloat16* __restrict__ dst, long n)
{
  long i = ((long)blockIdx.x * blockDim.x + threadIdx.x) * 8;
  if (i >= n) return;
  float4 a = *(const float4*)(src + i);
  float4 b = *(const float4*)(src + i + 4);
  unsigned long long o[2] = {pack4s(a, 1.f), pack4s(b, 1.f)};
  *(float4*)(dst + i) = *(const float4*)o;
}

// ---------------- bf16 NT MFMA GEMM (verified) ----------------
__global__ __launch_bounds__(256) void gemm_bf16_nt(
    const __hip_bfloat16* __restrict__ A, const __hip_bfloat16* __restrict__ W,
    float* __restrict__ C, int K, int ldc)
{
  __shared__ __hip_bfloat16 As[128 * 32];
  __shared__ __hip_bfloat16 Bs[128 * 32];
  const int m0 = blockIdx.y << 7, n0 = blockIdx.x << 7;
  const int t = threadIdx.x;
  const int wave = t >> 6, lane = t & 63;
  const int wr = wave >> 1, wc = wave & 1;

  f32x4 acc[4][4] = {};

  const int lrow4 = lane >> 2;
  const int lk8   = (lane & 3) * 8;
  const int fr    = lane & 15;
  const int fk    = (lane >> 4) * 8;

  for (int k0 = 0; k0 < K; k0 += 32) {
    __syncthreads();
#pragma unroll
    for (int p = 0; p < 2; ++p) {
      int rbase = p * 64 + wave * 16;
      const __hip_bfloat16* srcA = A + (size_t)(m0 + rbase + lrow4) * K + k0 + lk8;
      const __hip_bfloat16* srcB = W + (size_t)(n0 + rbase + lrow4) * K + k0 + lk8;
      __builtin_amdgcn_global_load_lds(
          (const __attribute__((address_space(1))) void*)srcA,
          (__attribute__((address_space(3))) void*)(As + rbase * 32), 16, 0, 0);
      __builtin_amdgcn_global_load_lds(
          (const __attribute__((address_space(1))) void*)srcB,
          (__attribute__((address_space(3))) void*)(Bs + rbase * 32), 16, 0, 0);
    }
    __syncthreads();

    bf16x8 af[4], bfr[4];
#pragma unroll
    for (int i = 0; i < 4; ++i) {
      af[i]  = *(const bf16x8*)(As + (wr * 64 + i * 16 + fr) * 32 + fk);
      bfr[i] = *(const bf16x8*)(Bs + (wc * 64 + i * 16 + fr) * 32 + fk);
    }
#pragma unroll
    for (int mi = 0; mi < 4; ++mi)
#pragma unroll
      for (int ni = 0; ni < 4; ++ni)
        acc[mi][ni] = __builtin_amdgcn_mfma_f32_16x16x32_bf16(af[mi], bfr[ni], acc[mi][ni], 0, 0, 0);
  }

#pragma unroll
  for (int mi = 0; mi < 4; ++mi) {
    int rbase = m0 + wr * 64 + mi * 16 + (lane >> 4) * 4;
#pragma unroll
    for (int ni = 0; ni < 4; ++ni) {
      int col = n0 + wc * 64 + ni * 16 + (lane & 15);
#pragma unroll
      for (int r = 0; r < 4; ++r)
        C[(size_t)(rbase + r) * ldc + col] = acc[mi][ni][r];
    }
  }
}

// ---------------- RoPE ----------------
__global__ void rope_kernel(float* __restrict__ Y, const int* __restrict__ pos_ids)
{
  int idx = blockIdx.x * blockDim.x + threadIdx.x;
  const int npairs = M_ * 40 * 32;
  if (idx >= npairs) return;
  int d    = idx & 31;
  int hr   = idx >> 5;
  int head = hr % 40;
  int m    = hr / 40;
  float* row = Y + (size_t)m * QKVN_;
  int col = head * 64 + d;
  float x0 = row[col], x1 = row[col + 32];
  float p = (float)(pos_ids[m] + 2);
  float inv = exp2f(-0.4152410118609203f * (float)d);   // 10000^(-2d/64)
  float f = p * inv;
  float c, s;
  sincosf(f, &s, &c);
  row[col]      = x0 * c - x1 * s;
  row[col + 32] = x1 * c + x0 * s;
}

// ---------------- MFMA flash attention, swapped-QK^T, bf16 ----------------
// 256 thr = 4 waves, QBLK=64 (16 q/wave), KVBLK=64.
// S^T = mfma(K,Q): lane owns q=lane&15, 16 k-scores in regs -> in-register softmax.
// Reg-staged K/V double-pipeline (issue t+1 loads before compute t).
__global__ __launch_bounds__(256) void attn_mfma(
    const float* __restrict__ Y,        // [M_][3072], rope applied
    const float* __restrict__ cache_k,  // [2][B][H][Q][64]
    const float* __restrict__ cache_v,
    unsigned short* __restrict__ AOb)   // [M_][2048] bf16
{
  __shared__ unsigned short Qs[64*64];
  __shared__ unsigned short Ks[64*64];
  __shared__ unsigned short Vt[64*64];
  __shared__ unsigned short Ps[64*64];   // 4 waves x [16][64] swizzled

  // XCD-grouped decomposition: each XCD gets 8 (h,b) pairs x all 16 q-tiles
  const int bid = blockIdx.x;
  const int xcd = bid & 7, within = bid >> 3;
  const int pair = xcd * 8 + (within & 7);
  const int qt = within >> 3;
  const int h = pair >> 1, b = pair & 1;

  const int t = threadIdx.x;
  const int wave = t >> 6, lane = t & 63;
  const int li = t >> 2, lseg = t & 3;
  const int g = lane >> 4, sub = lane & 15;
  const int wq0 = wave * 16;

  // ---- stage Q tile (scaled bf16, swizzled) ----
  {
    const float* qp = Y + (size_t)(b*Q_ + (qt<<6) + li)*QKVN_ + h*HD_ + lseg*16;
#pragma unroll
    for (int c = 0; c < 4; ++c) {
      float4 v = *(const float4*)(qp + 4*c);
      int k0 = lseg*16 + 4*c;
      int dst = li*64 + (((k0>>3) ^ (li&7))<<3) + (k0&7);
      *(unsigned long long*)&Qs[dst] = pack4s(v, SCALE_);
    }
  }

  const float* k0b = cache_k + (size_t)(b*H_ + h)*Q_*HD_;
  const float* v0b = cache_v + (size_t)(b*H_ + h)*Q_*HD_;

  // prefetch kt=0 into regs
  float4 kreg[4], vreg[4];
  {
    const float* kp = k0b + (size_t)li*HD_ + lseg*16;
    const float* vp = v0b + (size_t)li*HD_ + lseg*16;
#pragma unroll
    for (int c = 0; c < 4; ++c) {
      kreg[c] = *(const float4*)(kp + 4*c);
      vreg[c] = *(const float4*)(vp + 4*c);
    }
  }

  __syncthreads();

  // hoist Q fragments (B-operand: row=q=wq0+sub, k=(lane>>4)*8)
  bf16x8 qb[2];
#pragma unroll
  for (int kk = 0; kk < 2; ++kk) {
    int row = wq0 + sub;
    int kb = 4*kk + g;
    qb[kk] = *(const bf16x8*)&Qs[row*64 + ((kb ^ (row&7))<<3)];
  }

  float m_run = -3e38f, l_run = 0.f;
  f32x4 acc_o[4] = {};

  for (int kt = 0; kt <= qt; ++kt) {
    // ---- write staged K/V regs -> LDS ----
#pragma unroll
    for (int c = 0; c < 4; ++c) {
      int k0 = lseg*16 + 4*c;
      int dst = li*64 + (((k0>>3) ^ (li&7))<<3) + (k0&7);
      *(unsigned long long*)&Ks[dst] = pack4s(kreg[c], 1.f);
      float vv[4] = {vreg[c].x, vreg[c].y, vreg[c].z, vreg[c].w};
#pragma unroll
      for (int i = 0; i < 4; ++i) {
        int d = k0 + i;
        int gd = (d ^ (d>>3)) & 7;
        Vt[d*64 + (li ^ (gd<<3))] = f2b(vv[i]);
      }
    }
    __syncthreads();

    // ---- issue next tile's global loads (overlap with compute) ----
    if (kt < qt) {
      const float* kp = k0b + (size_t)(((kt+1)<<6) + li)*HD_ + lseg*16;
      const float* vp = v0b + (size_t)(((kt+1)<<6) + li)*HD_ + lseg*16;
#pragma unroll
      for (int c = 0; c < 4; ++c) {
        kreg[c] = *(const float4*)(kp + 4*c);
        vreg[c] = *(const float4*)(vp + 4*c);
      }
    }

    // ---- S^T = K Q^T: D col=q(sub), row=k=cb*16+g*4+r ----
    f32x4 s[4] = {};
    __builtin_amdgcn_s_setprio(1);
#pragma unroll
    for (int kk = 0; kk < 2; ++kk) {
      int kb = 4*kk + g;
#pragma unroll
      for (int cb = 0; cb < 4; ++cb) {
        int krow = cb*16 + sub;
        bf16x8 kf = *(const bf16x8*)&Ks[krow*64 + ((kb ^ (krow&7))<<3)];
        s[cb] = __builtin_amdgcn_mfma_f32_16x16x32_bf16(kf, qb[kk], s[cb], 0, 0, 0);
      }
    }
    __builtin_amdgcn_s_setprio(0);

    if (kt == qt) { // causal mask: k_loc > q_loc
#pragma unroll
      for (int cb = 0; cb < 4; ++cb)
#pragma unroll
        for (int r = 0; r < 4; ++r)
          if (cb*16 + 4*g + r > wq0 + sub) s[cb][r] = -3e38f;
    }

    // ---- in-register online softmax (lane owns q = wq0+sub) ----
    float mt = -3e38f;
#pragma unroll
    for (int cb = 0; cb < 4; ++cb)
#pragma unroll
      for (int r = 0; r < 4; ++r) mt = fmaxf(mt, s[cb][r]);
    mt = fmaxf(mt, __shfl_xor(mt, 16, 64));
    mt = fmaxf(mt, __shfl_xor(mt, 32, 64));
    float mnew = fmaxf(m_run, mt);
    float al = __expf(m_run - mnew);
    m_run = mnew;

    float sum = 0.f;
#pragma unroll
    for (int cb = 0; cb < 4; ++cb) {
      float p0 = __expf(s[cb][0]-mnew), p1 = __expf(s[cb][1]-mnew);
      float p2 = __expf(s[cb][2]-mnew), p3 = __expf(s[cb][3]-mnew);
      sum += (p0+p1)+(p2+p3);
      unsigned long long pk =
          (unsigned long long)((unsigned int)f2b(p0) | ((unsigned int)f2b(p1)<<16)) |
          ((unsigned long long)((unsigned int)f2b(p2) | ((unsigned int)f2b(p3)<<16)) << 32);
      int col8 = cb*2 + (g>>1);
      int dst = (wave*16 + sub)*64 + ((col8 ^ (sub&7))<<3) + ((g&1)<<2);
      *(unsigned long long*)&Ps[dst] = pk;
    }
    sum += __shfl_xor(sum, 16, 64);
    sum += __shfl_xor(sum, 32, 64);
    l_run = l_run*al + sum;

    // ---- rescale O rows (acc rows are q=wq0+4g+r) ----
    {
      int base = (lane & 48) + ((lane & 48) >> 2);
#pragma unroll
      for (int r = 0; r < 4; ++r) {
        float alr = __shfl(al, base + r, 64);
#pragma unroll
        for (int db = 0; db < 4; ++db) acc_o[db][r] *= alr;
      }
    }

    // ---- O += P V ----
    __builtin_amdgcn_s_setprio(1);
#pragma unroll
    for (int kk = 0; kk < 2; ++kk) {
      bf16x8 pa = *(const bf16x8*)&Ps[(wave*16 + sub)*64 + (((4*kk+g) ^ (sub&7))<<3)];
#pragma unroll
      for (int db = 0; db < 4; ++db) {
        int drow = db*16 + sub;
        int gd = (drow ^ (drow>>3)) & 7;
        bf16x8 vf = *(const bf16x8*)&Vt[drow*64 + (((4*kk+g) ^ gd)<<3)];
        acc_o[db] = __builtin_amdgcn_mfma_f32_16x16x32_bf16(pa, vf, acc_o[db], 0, 0, 0);
      }
    }
    __builtin_amdgcn_s_setprio(0);
    __syncthreads();   // protect LDS for next iteration's staging writes
  }

  // ---- tail: 2 extra keys ----
  const int qrow_mine = wq0 + sub;
  const int qpos_mine = (qt<<6) + qrow_mine;
  float e1 = 0.f, e2 = 0.f;
  {
    const float* k1p = cache_k + ((size_t)((B_ + b)*H_ + h)*Q_ + qpos_mine)*HD_ + g*16;
    const float* kfp = Y + (size_t)(b*Q_ + qpos_mine)*QKVN_ + H_*HD_ + (h/NREP_)*HD_ + g*16;
    float qv[16];
#pragma unroll
    for (int half = 0; half < 2; ++half) {
      int kb = 2*g + half;
      bf16x8 qq = *(const bf16x8*)&Qs[qrow_mine*64 + ((kb ^ (qrow_mine&7))<<3)];
#pragma unroll
      for (int i = 0; i < 8; ++i) qv[half*8 + i] = b2f(qq[i]);
    }
#pragma unroll
    for (int c = 0; c < 4; ++c) {
      float4 kv1 = *(const float4*)(k1p + 4*c);
      float4 kvf = *(const float4*)(kfp + 4*c);
      e1 += qv[4*c]*kv1.x + qv[4*c+1]*kv1.y + qv[4*c+2]*kv1.z + qv[4*c+3]*kv1.w;
      e2 += qv[4*c]*kvf.x + qv[4*c+1]*kvf.y + qv[4*c+2]*kvf.z + qv[4*c+3]*kvf.w;
    }
  }
  e1 += __shfl_xor(e1, 16, 64); e1 += __shfl_xor(e1, 32, 64);
  e2 += __shfl_xor(e2, 16, 64); e2 += __shfl_xor(e2, 32, 64);

#pragma unroll
  for (int r = 0; r < 4; ++r) {
    int row = 4*g + r;
    int src = (lane & 48) | row;
    float e1r = __shfl(e1, src, 64);
    float e2r = __shfl(e2, src, 64);
    float m_r = __shfl(m_run, src, 64);
    float l_r = __shfl(l_run, src, 64);
    float mnew = fmaxf(m_r, fmaxf(e1r, e2r));
    float alr = __expf(m_r - mnew);
    float w1  = __expf(e1r - mnew);
    float w2  = __expf(e2r - mnew);
    float linv = 1.f / (l_r*alr + w1 + w2);
    int qpos = (qt<<6) + wq0 + row;
    const float* v1p = cache_v + ((size_t)((B_ + b)*H_ + h)*Q_ + qpos)*HD_;
    const float* vfp = Y + (size_t)(b*Q_ + qpos)*QKVN_ + (H_*HD_ + KVH_*HD_) + (h/NREP_)*HD_;
    unsigned short* op = AOb + (size_t)(b*Q_ + qpos)*AOW_ + h*HD_;
#pragma unroll
    for (int db = 0; db < 4; ++db) {
      int d = db*16 + sub;
      float o = (acc_o[db][r]*alr + w1*v1p[d] + w2*vfp[d]) * linv;
      op[d] = f2b(o);
    }
  }
}

extern "C" void kernel_launch(void* const* d_in, const int* in_sizes, int n_in,
                              void* d_out, int out_size, void* d_ws, size_t ws_size,
                              hipStream_t stream) {
  const float* hidden  = (const float*)d_in[0];
  const float* Wq      = (const float*)d_in[1];
  const float* Wk      = (const float*)d_in[2];
  const float* Wv      = (const float*)d_in[3];
  const float* Wo      = (const float*)d_in[4];   // [HS][H*HD]
  const float* cache_k = (const float*)d_in[5];
  const float* cache_v = (const float*)d_in[6];
  const int*   pos_ids = (const int*)d_in[8];
  float* out = (float*)d_out;

  char* ws = (char*)d_ws;
  float* Y = (float*)ws;                                   // [2048][3072] fp32
  ws += (size_t)M_ * QKVN_ * 4;
  __hip_bfloat16* Xb  = (__hip_bfloat16*)ws;               // [2048][4096] bf16
  ws += (size_t)M_ * KIN_ * 2;
  __hip_bfloat16* Wb  = (__hip_bfloat16*)ws;               // [3072][4096] bf16
  ws += (size_t)QKVN_ * KIN_ * 2;
  __hip_bfloat16* Wob = (__hip_bfloat16*)ws;               // [2048][2048] bf16
  __hip_bfloat16* AOb = Xb;                                // Xb dead after QKV GEMM

  {
    long n;
    n = (long)M_ * KIN_;
    cast_f32_bf16<<<dim3((n/8 + 255)/256), 256, 0, stream>>>(hidden, Xb, n);
    n = (long)H_*HD_*KIN_;
    cast_f32_bf16<<<dim3((n/8 + 255)/256), 256, 0, stream>>>(Wq, Wb, n);
    n = (long)KVH_*HD_*KIN_;
    cast_f32_bf16<<<dim3((n/8 + 255)/256), 256, 0, stream>>>(Wk, Wb + (size_t)2048*KIN_, n);
    cast_f32_bf16<<<dim3((n/8 + 255)/256), 256, 0, stream>>>(Wv, Wb + (size_t)2560*KIN_, n);
    n = (long)HS_ * AOW_;
    cast_f32_bf16<<<dim3((n/8 + 255)/256), 256, 0, stream>>>(Wo, Wob, n);
  }

  gemm_bf16_nt<<<dim3(QKVN_/128, M_/128), 256, 0, stream>>>(Xb, Wb, Y, KIN_, QKVN_);
  rope_kernel<<<dim3((M_*40*32 + 255)/256), 256, 0, stream>>>(Y, pos_ids);
  attn_mfma<<<dim3(1024), 256, 0, stream>>>(Y, cache_k, cache_v, (unsigned short*)AOb);
  gemm_bf16_nt<<<dim3(HS_/128, M_/128), 256, 0, stream>>>(AOb, Wob, out, AOW_, HS_);
}

// Round 5
// 209.448 us; speedup vs baseline: 6.8635x; 1.1328x over previous
//
#include <hip/hip_runtime.h>
#include <hip/hip_bf16.h>
#include <math.h>

#define B_    2
#define Q_    1024
#define H_    32
#define KVH_  8
#define HD_   64
#define HS_   2048
#define NREP_ 4
#define KIN_  (2*HS_)            // 4096
#define M_    (B_*Q_)            // 2048
#define QKVN_ (H_*HD_ + 2*KVH_*HD_)  // 3072
#define AOW_  (H_*HD_)           // 2048
#define SCALE_ 0.125f            // 1/sqrt(64)

typedef __attribute__((ext_vector_type(8))) short bf16x8;
typedef __attribute__((ext_vector_type(4))) float f32x4;

static __device__ __forceinline__ unsigned short f2b(float f) {
  union { float f; unsigned int u; } c; c.f = f;
  unsigned int r = (c.u + 0x7fffu + ((c.u >> 16) & 1u)) >> 16;
  return (unsigned short)r;
}
static __device__ __forceinline__ float b2f(short s) {
  union { unsigned int u; float f; } c;
  c.u = ((unsigned int)(unsigned short)s) << 16;
  return c.f;
}
static __device__ __forceinline__ unsigned long long pack4s(float4 v, float sc) {
  return (unsigned long long)f2b(v.x*sc) |
         ((unsigned long long)f2b(v.y*sc) << 16) |
         ((unsigned long long)f2b(v.z*sc) << 32) |
         ((unsigned long long)f2b(v.w*sc) << 48);
}

// ---------------- fp32 -> bf16 cast ----------------
__global__ __launch_bounds__(256) void cast_f32_bf16(
    const float* __restrict__ src, __hip_bfloat16* __restrict__ dst, long n)
{
  long i = ((long)blockIdx.x * blockDim.x + threadIdx.x) * 8;
  if (i >= n) return;
  float4 a = *(const float4*)(src + i);
  float4 b = *(const float4*)(src + i + 4);
  unsigned long long o[2] = {pack4s(a, 1.f), pack4s(b, 1.f)};
  *(float4*)(dst + i) = *(const float4*)o;
}

// ---------------- bf16 NT MFMA GEMM, 128x64 tile for occupancy ----------------
// C[m][n] = sum_k A[m][k]*W[n][k].  BM=128, BN=64, BK=32, 256 thr = 4 waves (2x2),
// per-wave 64x32 output = 4x2 16x16 frags.  More blocks/CU than 128x128 at mid shapes.
__global__ __launch_bounds__(256, 4) void gemm_bf16_nt(
    const __hip_bfloat16* __restrict__ A, const __hip_bfloat16* __restrict__ W,
    float* __restrict__ C, int K, int ldc)
{
  __shared__ __hip_bfloat16 As[128 * 32];
  __shared__ __hip_bfloat16 Bs[64 * 32];
  const int m0 = blockIdx.y << 7, n0 = blockIdx.x << 6;
  const int t = threadIdx.x;
  const int wave = t >> 6, lane = t & 63;
  const int wr = wave >> 1, wc = wave & 1;

  f32x4 acc[4][2] = {};

  const int lrow4 = lane >> 2;          // 0..15 row within 16-row stripe
  const int lk8   = (lane & 3) * 8;     // k element offset (16B)
  const int fr    = lane & 15;
  const int fk    = (lane >> 4) * 8;

  for (int k0 = 0; k0 < K; k0 += 32) {
    __syncthreads();
    {
      // A: 128 rows in 2 rounds of 4-wave stripes
#pragma unroll
      for (int p = 0; p < 2; ++p) {
        int rbase = p * 64 + wave * 16;
        const __hip_bfloat16* srcA = A + (size_t)(m0 + rbase + lrow4) * K + k0 + lk8;
        __builtin_amdgcn_global_load_lds(
            (const __attribute__((address_space(1))) void*)srcA,
            (__attribute__((address_space(3))) void*)(As + rbase * 32), 16, 0, 0);
      }
      // B: 64 rows in 1 round
      int rbase = wave * 16;
      const __hip_bfloat16* srcB = W + (size_t)(n0 + rbase + lrow4) * K + k0 + lk8;
      __builtin_amdgcn_global_load_lds(
          (const __attribute__((address_space(1))) void*)srcB,
          (__attribute__((address_space(3))) void*)(Bs + rbase * 32), 16, 0, 0);
    }
    __syncthreads();

    bf16x8 af[4], bfr[2];
#pragma unroll
    for (int i = 0; i < 4; ++i)
      af[i]  = *(const bf16x8*)(As + (wr * 64 + i * 16 + fr) * 32 + fk);
#pragma unroll
    for (int j = 0; j < 2; ++j)
      bfr[j] = *(const bf16x8*)(Bs + (wc * 32 + j * 16 + fr) * 32 + fk);
#pragma unroll
    for (int mi = 0; mi < 4; ++mi)
#pragma unroll
      for (int ni = 0; ni < 2; ++ni)
        acc[mi][ni] = __builtin_amdgcn_mfma_f32_16x16x32_bf16(af[mi], bfr[ni], acc[mi][ni], 0, 0, 0);
  }

#pragma unroll
  for (int mi = 0; mi < 4; ++mi) {
    int rbase = m0 + wr * 64 + mi * 16 + (lane >> 4) * 4;
#pragma unroll
    for (int ni = 0; ni < 2; ++ni) {
      int col = n0 + wc * 32 + ni * 16 + (lane & 15);
#pragma unroll
      for (int r = 0; r < 4; ++r)
        C[(size_t)(rbase + r) * ldc + col] = acc[mi][ni][r];
    }
  }
}

// ---------------- RoPE ----------------
__global__ void rope_kernel(float* __restrict__ Y, const int* __restrict__ pos_ids)
{
  int idx = blockIdx.x * blockDim.x + threadIdx.x;
  const int npairs = M_ * 40 * 32;
  if (idx >= npairs) return;
  int d    = idx & 31;
  int hr   = idx >> 5;
  int head = hr % 40;
  int m    = hr / 40;
  float* row = Y + (size_t)m * QKVN_;
  int col = head * 64 + d;
  float x0 = row[col], x1 = row[col + 32];
  float p = (float)(pos_ids[m] + 2);
  float inv = exp2f(-0.4152410118609203f * (float)d);   // 10000^(-2d/64)
  float f = p * inv;
  float c, s;
  sincosf(f, &s, &c);
  row[col]      = x0 * c - x1 * s;
  row[col + 32] = x1 * c + x0 * s;
}

// ---------------- MFMA flash attention, swapped-QK^T, bf16 (round-4, passing) ----------------
__global__ __launch_bounds__(256) void attn_mfma(
    const float* __restrict__ Y,        // [M_][3072], rope applied
    const float* __restrict__ cache_k,  // [2][B][H][Q][64]
    const float* __restrict__ cache_v,
    unsigned short* __restrict__ AOb)   // [M_][2048] bf16
{
  __shared__ unsigned short Qs[64*64];
  __shared__ unsigned short Ks[64*64];
  __shared__ unsigned short Vt[64*64];
  __shared__ unsigned short Ps[64*64];

  const int bid = blockIdx.x;
  const int xcd = bid & 7, within = bid >> 3;
  const int pair = xcd * 8 + (within & 7);
  const int qt = within >> 3;
  const int h = pair >> 1, b = pair & 1;

  const int t = threadIdx.x;
  const int wave = t >> 6, lane = t & 63;
  const int li = t >> 2, lseg = t & 3;
  const int g = lane >> 4, sub = lane & 15;
  const int wq0 = wave * 16;

  {
    const float* qp = Y + (size_t)(b*Q_ + (qt<<6) + li)*QKVN_ + h*HD_ + lseg*16;
#pragma unroll
    for (int c = 0; c < 4; ++c) {
      float4 v = *(const float4*)(qp + 4*c);
      int k0 = lseg*16 + 4*c;
      int dst = li*64 + (((k0>>3) ^ (li&7))<<3) + (k0&7);
      *(unsigned long long*)&Qs[dst] = pack4s(v, SCALE_);
    }
  }

  const float* k0b = cache_k + (size_t)(b*H_ + h)*Q_*HD_;
  const float* v0b = cache_v + (size_t)(b*H_ + h)*Q_*HD_;

  float4 kreg[4], vreg[4];
  {
    const float* kp = k0b + (size_t)li*HD_ + lseg*16;
    const float* vp = v0b + (size_t)li*HD_ + lseg*16;
#pragma unroll
    for (int c = 0; c < 4; ++c) {
      kreg[c] = *(const float4*)(kp + 4*c);
      vreg[c] = *(const float4*)(vp + 4*c);
    }
  }

  __syncthreads();

  bf16x8 qb[2];
#pragma unroll
  for (int kk = 0; kk < 2; ++kk) {
    int row = wq0 + sub;
    int kb = 4*kk + g;
    qb[kk] = *(const bf16x8*)&Qs[row*64 + ((kb ^ (row&7))<<3)];
  }

  float m_run = -3e38f, l_run = 0.f;
  f32x4 acc_o[4] = {};

  for (int kt = 0; kt <= qt; ++kt) {
#pragma unroll
    for (int c = 0; c < 4; ++c) {
      int k0 = lseg*16 + 4*c;
      int dst = li*64 + (((k0>>3) ^ (li&7))<<3) + (k0&7);
      *(unsigned long long*)&Ks[dst] = pack4s(kreg[c], 1.f);
      float vv[4] = {vreg[c].x, vreg[c].y, vreg[c].z, vreg[c].w};
#pragma unroll
      for (int i = 0; i < 4; ++i) {
        int d = k0 + i;
        int gd = (d ^ (d>>3)) & 7;
        Vt[d*64 + (li ^ (gd<<3))] = f2b(vv[i]);
      }
    }
    __syncthreads();

    if (kt < qt) {
      const float* kp = k0b + (size_t)(((kt+1)<<6) + li)*HD_ + lseg*16;
      const float* vp = v0b + (size_t)(((kt+1)<<6) + li)*HD_ + lseg*16;
#pragma unroll
      for (int c = 0; c < 4; ++c) {
        kreg[c] = *(const float4*)(kp + 4*c);
        vreg[c] = *(const float4*)(vp + 4*c);
      }
    }

    f32x4 s[4] = {};
    __builtin_amdgcn_s_setprio(1);
#pragma unroll
    for (int kk = 0; kk < 2; ++kk) {
      int kb = 4*kk + g;
#pragma unroll
      for (int cb = 0; cb < 4; ++cb) {
        int krow = cb*16 + sub;
        bf16x8 kf = *(const bf16x8*)&Ks[krow*64 + ((kb ^ (krow&7))<<3)];
        s[cb] = __builtin_amdgcn_mfma_f32_16x16x32_bf16(kf, qb[kk], s[cb], 0, 0, 0);
      }
    }
    __builtin_amdgcn_s_setprio(0);

    if (kt == qt) {
#pragma unroll
      for (int cb = 0; cb < 4; ++cb)
#pragma unroll
        for (int r = 0; r < 4; ++r)
          if (cb*16 + 4*g + r > wq0 + sub) s[cb][r] = -3e38f;
    }

    float mt = -3e38f;
#pragma unroll
    for (int cb = 0; cb < 4; ++cb)
#pragma unroll
      for (int r = 0; r < 4; ++r) mt = fmaxf(mt, s[cb][r]);
    mt = fmaxf(mt, __shfl_xor(mt, 16, 64));
    mt = fmaxf(mt, __shfl_xor(mt, 32, 64));
    float mnew = fmaxf(m_run, mt);
    float al = __expf(m_run - mnew);
    m_run = mnew;

    float sum = 0.f;
#pragma unroll
    for (int cb = 0; cb < 4; ++cb) {
      float p0 = __expf(s[cb][0]-mnew), p1 = __expf(s[cb][1]-mnew);
      float p2 = __expf(s[cb][2]-mnew), p3 = __expf(s[cb][3]-mnew);
      sum += (p0+p1)+(p2+p3);
      unsigned long long pk =
          (unsigned long long)((unsigned int)f2b(p0) | ((unsigned int)f2b(p1)<<16)) |
          ((unsigned long long)((unsigned int)f2b(p2) | ((unsigned int)f2b(p3)<<16)) << 32);
      int col8 = cb*2 + (g>>1);
      int dst = (wave*16 + sub)*64 + ((col8 ^ (sub&7))<<3) + ((g&1)<<2);
      *(unsigned long long*)&Ps[dst] = pk;
    }
    sum += __shfl_xor(sum, 16, 64);
    sum += __shfl_xor(sum, 32, 64);
    l_run = l_run*al + sum;

    {
      int base = (lane & 48) + ((lane & 48) >> 2);
#pragma unroll
      for (int r = 0; r < 4; ++r) {
        float alr = __shfl(al, base + r, 64);
#pragma unroll
        for (int db = 0; db < 4; ++db) acc_o[db][r] *= alr;
      }
    }

    __builtin_amdgcn_s_setprio(1);
#pragma unroll
    for (int kk = 0; kk < 2; ++kk) {
      bf16x8 pa = *(const bf16x8*)&Ps[(wave*16 + sub)*64 + (((4*kk+g) ^ (sub&7))<<3)];
#pragma unroll
      for (int db = 0; db < 4; ++db) {
        int drow = db*16 + sub;
        int gd = (drow ^ (drow>>3)) & 7;
        bf16x8 vf = *(const bf16x8*)&Vt[drow*64 + (((4*kk+g) ^ gd)<<3)];
        acc_o[db] = __builtin_amdgcn_mfma_f32_16x16x32_bf16(pa, vf, acc_o[db], 0, 0, 0);
      }
    }
    __builtin_amdgcn_s_setprio(0);
    __syncthreads();
  }

  const int qrow_mine = wq0 + sub;
  const int qpos_mine = (qt<<6) + qrow_mine;
  float e1 = 0.f, e2 = 0.f;
  {
    const float* k1p = cache_k + ((size_t)((B_ + b)*H_ + h)*Q_ + qpos_mine)*HD_ + g*16;
    const float* kfp = Y + (size_t)(b*Q_ + qpos_mine)*QKVN_ + H_*HD_ + (h/NREP_)*HD_ + g*16;
    float qv[16];
#pragma unroll
    for (int half = 0; half < 2; ++half) {
      int kb = 2*g + half;
      bf16x8 qq = *(const bf16x8*)&Qs[qrow_mine*64 + ((kb ^ (qrow_mine&7))<<3)];
#pragma unroll
      for (int i = 0; i < 8; ++i) qv[half*8 + i] = b2f(qq[i]);
    }
#pragma unroll
    for (int c = 0; c < 4; ++c) {
      float4 kv1 = *(const float4*)(k1p + 4*c);
      float4 kvf = *(const float4*)(kfp + 4*c);
      e1 += qv[4*c]*kv1.x + qv[4*c+1]*kv1.y + qv[4*c+2]*kv1.z + qv[4*c+3]*kv1.w;
      e2 += qv[4*c]*kvf.x + qv[4*c+1]*kvf.y + qv[4*c+2]*kvf.z + qv[4*c+3]*kvf.w;
    }
  }
  e1 += __shfl_xor(e1, 16, 64); e1 += __shfl_xor(e1, 32, 64);
  e2 += __shfl_xor(e2, 16, 64); e2 += __shfl_xor(e2, 32, 64);

#pragma unroll
  for (int r = 0; r < 4; ++r) {
    int row = 4*g + r;
    int src = (lane & 48) | row;
    float e1r = __shfl(e1, src, 64);
    float e2r = __shfl(e2, src, 64);
    float m_r = __shfl(m_run, src, 64);
    float l_r = __shfl(l_run, src, 64);
    float mnew = fmaxf(m_r, fmaxf(e1r, e2r));
    float alr = __expf(m_r - mnew);
    float w1  = __expf(e1r - mnew);
    float w2  = __expf(e2r - mnew);
    float linv = 1.f / (l_r*alr + w1 + w2);
    int qpos = (qt<<6) + wq0 + row;
    const float* v1p = cache_v + ((size_t)((B_ + b)*H_ + h)*Q_ + qpos)*HD_;
    const float* vfp = Y + (size_t)(b*Q_ + qpos)*QKVN_ + (H_*HD_ + KVH_*HD_) + (h/NREP_)*HD_;
    unsigned short* op = AOb + (size_t)(b*Q_ + qpos)*AOW_ + h*HD_;
#pragma unroll
    for (int db = 0; db < 4; ++db) {
      int d = db*16 + sub;
      float o = (acc_o[db][r]*alr + w1*v1p[d] + w2*vfp[d]) * linv;
      op[d] = f2b(o);
    }
  }
}

extern "C" void kernel_launch(void* const* d_in, const int* in_sizes, int n_in,
                              void* d_out, int out_size, void* d_ws, size_t ws_size,
                              hipStream_t stream) {
  const float* hidden  = (const float*)d_in[0];
  const float* Wq      = (const float*)d_in[1];
  const float* Wk      = (const float*)d_in[2];
  const float* Wv      = (const float*)d_in[3];
  const float* Wo      = (const float*)d_in[4];   // [HS][H*HD]
  const float* cache_k = (const float*)d_in[5];
  const float* cache_v = (const float*)d_in[6];
  const int*   pos_ids = (const int*)d_in[8];
  float* out = (float*)d_out;

  char* ws = (char*)d_ws;
  float* Y = (float*)ws;                                   // [2048][3072] fp32
  ws += (size_t)M_ * QKVN_ * 4;
  __hip_bfloat16* Xb  = (__hip_bfloat16*)ws;               // [2048][4096] bf16
  ws += (size_t)M_ * KIN_ * 2;
  __hip_bfloat16* Wb  = (__hip_bfloat16*)ws;               // [3072][4096] bf16
  ws += (size_t)QKVN_ * KIN_ * 2;
  __hip_bfloat16* Wob = (__hip_bfloat16*)ws;               // [2048][2048] bf16
  __hip_bfloat16* AOb = Xb;                                // Xb dead after QKV GEMM

  {
    long n;
    n = (long)M_ * KIN_;
    cast_f32_bf16<<<dim3((n/8 + 255)/256), 256, 0, stream>>>(hidden, Xb, n);
    n = (long)H_*HD_*KIN_;
    cast_f32_bf16<<<dim3((n/8 + 255)/256), 256, 0, stream>>>(Wq, Wb, n);
    n = (long)KVH_*HD_*KIN_;
    cast_f32_bf16<<<dim3((n/8 + 255)/256), 256, 0, stream>>>(Wk, Wb + (size_t)2048*KIN_, n);
    cast_f32_bf16<<<dim3((n/8 + 255)/256), 256, 0, stream>>>(Wv, Wb + (size_t)2560*KIN_, n);
    n = (long)HS_ * AOW_;
    cast_f32_bf16<<<dim3((n/8 + 255)/256), 256, 0, stream>>>(Wo, Wob, n);
  }

  // QKV: [2048][4096] x [3072][4096]^T -> Y; grid 48x16 = 768 blocks (3/CU)
  gemm_bf16_nt<<<dim3(QKVN_/64, M_/128), 256, 0, stream>>>(Xb, Wb, Y, KIN_, QKVN_);
  rope_kernel<<<dim3((M_*40*32 + 255)/256), 256, 0, stream>>>(Y, pos_ids);
  attn_mfma<<<dim3(1024), 256, 0, stream>>>(Y, cache_k, cache_v, (unsigned short*)AOb);
  // Wo: grid 32x16 = 512 blocks (2/CU)
  gemm_bf16_nt<<<dim3(HS_/64, M_/128), 256, 0, stream>>>(AOb, Wob, out, AOW_, HS_);
}

// Round 6
// 185.797 us; speedup vs baseline: 7.7372x; 1.1273x over previous
//
#include <hip/hip_runtime.h>
#include <hip/hip_bf16.h>
#include <math.h>

#define B_    2
#define Q_    1024
#define H_    32
#define KVH_  8
#define HD_   64
#define HS_   2048
#define NREP_ 4
#define KIN_  (2*HS_)            // 4096
#define M_    (B_*Q_)            // 2048
#define QKVN_ (H_*HD_ + 2*KVH_*HD_)  // 3072
#define AOW_  (H_*HD_)           // 2048
#define SCALE_ 0.125f            // 1/sqrt(64)

typedef __attribute__((ext_vector_type(8))) short bf16x8;
typedef __attribute__((ext_vector_type(4))) float f32x4;

static __device__ __forceinline__ unsigned short f2b(float f) {
  union { float f; unsigned int u; } c; c.f = f;
  unsigned int r = (c.u + 0x7fffu + ((c.u >> 16) & 1u)) >> 16;
  return (unsigned short)r;
}
static __device__ __forceinline__ float b2f(short s) {
  union { unsigned int u; float f; } c;
  c.u = ((unsigned int)(unsigned short)s) << 16;
  return c.f;
}
static __device__ __forceinline__ unsigned long long pack4s(float4 v, float sc) {
  return (unsigned long long)f2b(v.x*sc) |
         ((unsigned long long)f2b(v.y*sc) << 16) |
         ((unsigned long long)f2b(v.z*sc) << 32) |
         ((unsigned long long)f2b(v.w*sc) << 48);
}

// ---------------- fp32 -> bf16 cast ----------------
__global__ __launch_bounds__(256) void cast_f32_bf16(
    const float* __restrict__ src, __hip_bfloat16* __restrict__ dst, long n)
{
  long i = ((long)blockIdx.x * blockDim.x + threadIdx.x) * 8;
  if (i >= n) return;
  float4 a = *(const float4*)(src + i);
  float4 b = *(const float4*)(src + i + 4);
  unsigned long long o[2] = {pack4s(a, 1.f), pack4s(b, 1.f)};
  *(float4*)(dst + i) = *(const float4*)o;
}

// ---------------- bf16 NT MFMA GEMM, 128x64 tile, BK=64, swizzled LDS ----------------
// C[m][n] = sum_k A[m][k]*W[n][k].  BM=128, BN=64, BK=64, 256 thr = 4 waves (2x2),
// per-wave 64x32 = 4x2 16x16 frags, kk in {0,1}.
// LDS rows are 128B (64 bf16).  Swizzle: 16B-chunk c of row r lives at chunk c^(r&7).
// Stage: global source pre-swizzled (chunk = (lane&7)^(lane>>3)), LDS dest linear
// (global_load_lds rule) -> involution holds; reads XOR with (row&7).  Spreads each
// wave b128 read over all 8 bank slots (was 4 -> ~2x read penalty + 9.4e6 conflicts).
__global__ __launch_bounds__(256, 4) void gemm_bf16_nt(
    const __hip_bfloat16* __restrict__ A, const __hip_bfloat16* __restrict__ W,
    float* __restrict__ C, int K, int ldc)
{
  __shared__ __hip_bfloat16 As[128 * 64];   // 16 KB
  __shared__ __hip_bfloat16 Bs[64 * 64];    // 8 KB
  const int m0 = blockIdx.y << 7, n0 = blockIdx.x << 6;
  const int t = threadIdx.x;
  const int wave = t >> 6, lane = t & 63;
  const int wr = wave >> 1, wc = wave & 1;

  f32x4 acc[4][2] = {};

  const int lrow8 = lane >> 3;                 // 0..7 row within 8-row stripe
  const int lcsw  = ((lane & 7) ^ lrow8) * 8;  // pre-swizzled k-chunk (elements)
  const int fr    = lane & 15;
  const int g     = lane >> 4;                 // 0..3

  for (int k0 = 0; k0 < K; k0 += 64) {
    __syncthreads();
    {
      // A: 128 rows in 4 rounds of (4 waves x 8 rows)
#pragma unroll
      for (int p = 0; p < 4; ++p) {
        int rbase = p * 32 + wave * 8;
        const __hip_bfloat16* srcA = A + (size_t)(m0 + rbase + lrow8) * K + k0 + lcsw;
        __builtin_amdgcn_global_load_lds(
            (const __attribute__((address_space(1))) void*)srcA,
            (__attribute__((address_space(3))) void*)(As + rbase * 64), 16, 0, 0);
      }
      // B: 64 rows in 2 rounds
#pragma unroll
      for (int p = 0; p < 2; ++p) {
        int rbase = p * 32 + wave * 8;
        const __hip_bfloat16* srcB = W + (size_t)(n0 + rbase + lrow8) * K + k0 + lcsw;
        __builtin_amdgcn_global_load_lds(
            (const __attribute__((address_space(1))) void*)srcB,
            (__attribute__((address_space(3))) void*)(Bs + rbase * 64), 16, 0, 0);
      }
    }
    __syncthreads();

    bf16x8 af[4][2], bfr[2][2];
#pragma unroll
    for (int kk = 0; kk < 2; ++kk) {
      int ck = kk * 4 + g;                     // global k-chunk 0..7
#pragma unroll
      for (int mi = 0; mi < 4; ++mi) {
        int row = wr * 64 + mi * 16 + fr;
        af[mi][kk] = *(const bf16x8*)(As + row * 64 + ((ck ^ (row & 7)) << 3));
      }
#pragma unroll
      for (int ni = 0; ni < 2; ++ni) {
        int row = wc * 32 + ni * 16 + fr;
        bfr[ni][kk] = *(const bf16x8*)(Bs + row * 64 + ((ck ^ (row & 7)) << 3));
      }
    }
#pragma unroll
    for (int kk = 0; kk < 2; ++kk)
#pragma unroll
      for (int mi = 0; mi < 4; ++mi)
#pragma unroll
        for (int ni = 0; ni < 2; ++ni)
          acc[mi][ni] = __builtin_amdgcn_mfma_f32_16x16x32_bf16(af[mi][kk], bfr[ni][kk], acc[mi][ni], 0, 0, 0);
  }

#pragma unroll
  for (int mi = 0; mi < 4; ++mi) {
    int rbase = m0 + wr * 64 + mi * 16 + (lane >> 4) * 4;
#pragma unroll
    for (int ni = 0; ni < 2; ++ni) {
      int col = n0 + wc * 32 + ni * 16 + (lane & 15);
#pragma unroll
      for (int r = 0; r < 4; ++r)
        C[(size_t)(rbase + r) * ldc + col] = acc[mi][ni][r];
    }
  }
}

// ---------------- RoPE ----------------
__global__ void rope_kernel(float* __restrict__ Y, const int* __restrict__ pos_ids)
{
  int idx = blockIdx.x * blockDim.x + threadIdx.x;
  const int npairs = M_ * 40 * 32;
  if (idx >= npairs) return;
  int d    = idx & 31;
  int hr   = idx >> 5;
  int head = hr % 40;
  int m    = hr / 40;
  float* row = Y + (size_t)m * QKVN_;
  int col = head * 64 + d;
  float x0 = row[col], x1 = row[col + 32];
  float p = (float)(pos_ids[m] + 2);
  float inv = exp2f(-0.4152410118609203f * (float)d);   // 10000^(-2d/64)
  float f = p * inv;
  float c, s;
  sincosf(f, &s, &c);
  row[col]      = x0 * c - x1 * s;
  row[col + 32] = x1 * c + x0 * s;
}

// ---------------- MFMA flash attention, swapped-QK^T, bf16 ----------------
// Block order: qt-major within an (h,b) pair, pairs sequential per XCD -> working
// set per XCD at a time = one pair's K0/V0 (1 MB) <= 4 MB L2 (was 8 pairs = 8 MB, thrash).
__global__ __launch_bounds__(256) void attn_mfma(
    const float* __restrict__ Y,        // [M_][3072], rope applied
    const float* __restrict__ cache_k,  // [2][B][H][Q][64]
    const float* __restrict__ cache_v,
    unsigned short* __restrict__ AOb)   // [M_][2048] bf16
{
  __shared__ unsigned short Qs[64*64];
  __shared__ unsigned short Ks[64*64];
  __shared__ unsigned short Vt[64*64];
  __shared__ unsigned short Ps[64*64];

  const int bid = blockIdx.x;
  const int xcd = bid & 7, within = bid >> 3;
  const int qt = within & 15;                 // qt-major: 16 q-tiles of one pair
  const int pair = xcd * 8 + (within >> 4);   // then next pair on this XCD
  const int h = pair >> 1, b = pair & 1;

  const int t = threadIdx.x;
  const int wave = t >> 6, lane = t & 63;
  const int li = t >> 2, lseg = t & 3;
  const int g = lane >> 4, sub = lane & 15;
  const int wq0 = wave * 16;

  {
    const float* qp = Y + (size_t)(b*Q_ + (qt<<6) + li)*QKVN_ + h*HD_ + lseg*16;
#pragma unroll
    for (int c = 0; c < 4; ++c) {
      float4 v = *(const float4*)(qp + 4*c);
      int k0 = lseg*16 + 4*c;
      int dst = li*64 + (((k0>>3) ^ (li&7))<<3) + (k0&7);
      *(unsigned long long*)&Qs[dst] = pack4s(v, SCALE_);
    }
  }

  const float* k0b = cache_k + (size_t)(b*H_ + h)*Q_*HD_;
  const float* v0b = cache_v + (size_t)(b*H_ + h)*Q_*HD_;

  float4 kreg[4], vreg[4];
  {
    const float* kp = k0b + (size_t)li*HD_ + lseg*16;
    const float* vp = v0b + (size_t)li*HD_ + lseg*16;
#pragma unroll
    for (int c = 0; c < 4; ++c) {
      kreg[c] = *(const float4*)(kp + 4*c);
      vreg[c] = *(const float4*)(vp + 4*c);
    }
  }

  __syncthreads();

  bf16x8 qb[2];
#pragma unroll
  for (int kk = 0; kk < 2; ++kk) {
    int row = wq0 + sub;
    int kb = 4*kk + g;
    qb[kk] = *(const bf16x8*)&Qs[row*64 + ((kb ^ (row&7))<<3)];
  }

  float m_run = -3e38f, l_run = 0.f;
  f32x4 acc_o[4] = {};

  for (int kt = 0; kt <= qt; ++kt) {
#pragma unroll
    for (int c = 0; c < 4; ++c) {
      int k0 = lseg*16 + 4*c;
      int dst = li*64 + (((k0>>3) ^ (li&7))<<3) + (k0&7);
      *(unsigned long long*)&Ks[dst] = pack4s(kreg[c], 1.f);
      float vv[4] = {vreg[c].x, vreg[c].y, vreg[c].z, vreg[c].w};
#pragma unroll
      for (int i = 0; i < 4; ++i) {
        int d = k0 + i;
        int gd = (d ^ (d>>3)) & 7;
        Vt[d*64 + (li ^ (gd<<3))] = f2b(vv[i]);
      }
    }
    __syncthreads();

    if (kt < qt) {
      const float* kp = k0b + (size_t)(((kt+1)<<6) + li)*HD_ + lseg*16;
      const float* vp = v0b + (size_t)(((kt+1)<<6) + li)*HD_ + lseg*16;
#pragma unroll
      for (int c = 0; c < 4; ++c) {
        kreg[c] = *(const float4*)(kp + 4*c);
        vreg[c] = *(const float4*)(vp + 4*c);
      }
    }

    f32x4 s[4] = {};
    __builtin_amdgcn_s_setprio(1);
#pragma unroll
    for (int kk = 0; kk < 2; ++kk) {
      int kb = 4*kk + g;
#pragma unroll
      for (int cb = 0; cb < 4; ++cb) {
        int krow = cb*16 + sub;
        bf16x8 kf = *(const bf16x8*)&Ks[krow*64 + ((kb ^ (krow&7))<<3)];
        s[cb] = __builtin_amdgcn_mfma_f32_16x16x32_bf16(kf, qb[kk], s[cb], 0, 0, 0);
      }
    }
    __builtin_amdgcn_s_setprio(0);

    if (kt == qt) {
#pragma unroll
      for (int cb = 0; cb < 4; ++cb)
#pragma unroll
        for (int r = 0; r < 4; ++r)
          if (cb*16 + 4*g + r > wq0 + sub) s[cb][r] = -3e38f;
    }

    float mt = -3e38f;
#pragma unroll
    for (int cb = 0; cb < 4; ++cb)
#pragma unroll
      for (int r = 0; r < 4; ++r) mt = fmaxf(mt, s[cb][r]);
    mt = fmaxf(mt, __shfl_xor(mt, 16, 64));
    mt = fmaxf(mt, __shfl_xor(mt, 32, 64));
    float mnew = fmaxf(m_run, mt);
    float al = __expf(m_run - mnew);
    m_run = mnew;

    float sum = 0.f;
#pragma unroll
    for (int cb = 0; cb < 4; ++cb) {
      float p0 = __expf(s[cb][0]-mnew), p1 = __expf(s[cb][1]-mnew);
      float p2 = __expf(s[cb][2]-mnew), p3 = __expf(s[cb][3]-mnew);
      sum += (p0+p1)+(p2+p3);
      unsigned long long pk =
          (unsigned long long)((unsigned int)f2b(p0) | ((unsigned int)f2b(p1)<<16)) |
          ((unsigned long long)((unsigned int)f2b(p2) | ((unsigned int)f2b(p3)<<16)) << 32);
      int col8 = cb*2 + (g>>1);
      int dst = (wave*16 + sub)*64 + ((col8 ^ (sub&7))<<3) + ((g&1)<<2);
      *(unsigned long long*)&Ps[dst] = pk;
    }
    sum += __shfl_xor(sum, 16, 64);
    sum += __shfl_xor(sum, 32, 64);
    l_run = l_run*al + sum;

    {
      int base = (lane & 48) + ((lane & 48) >> 2);
#pragma unroll
      for (int r = 0; r < 4; ++r) {
        float alr = __shfl(al, base + r, 64);
#pragma unroll
        for (int db = 0; db < 4; ++db) acc_o[db][r] *= alr;
      }
    }

    __builtin_amdgcn_s_setprio(1);
#pragma unroll
    for (int kk = 0; kk < 2; ++kk) {
      bf16x8 pa = *(const bf16x8*)&Ps[(wave*16 + sub)*64 + (((4*kk+g) ^ (sub&7))<<3)];
#pragma unroll
      for (int db = 0; db < 4; ++db) {
        int drow = db*16 + sub;
        int gd = (drow ^ (drow>>3)) & 7;
        bf16x8 vf = *(const bf16x8*)&Vt[drow*64 + (((4*kk+g) ^ gd)<<3)];
        acc_o[db] = __builtin_amdgcn_mfma_f32_16x16x32_bf16(pa, vf, acc_o[db], 0, 0, 0);
      }
    }
    __builtin_amdgcn_s_setprio(0);
    __syncthreads();
  }

  const int qrow_mine = wq0 + sub;
  const int qpos_mine = (qt<<6) + qrow_mine;
  float e1 = 0.f, e2 = 0.f;
  {
    const float* k1p = cache_k + ((size_t)((B_ + b)*H_ + h)*Q_ + qpos_mine)*HD_ + g*16;
    const float* kfp = Y + (size_t)(b*Q_ + qpos_mine)*QKVN_ + H_*HD_ + (h/NREP_)*HD_ + g*16;
    float qv[16];
#pragma unroll
    for (int half = 0; half < 2; ++half) {
      int kb = 2*g + half;
      bf16x8 qq = *(const bf16x8*)&Qs[qrow_mine*64 + ((kb ^ (qrow_mine&7))<<3)];
#pragma unroll
      for (int i = 0; i < 8; ++i) qv[half*8 + i] = b2f(qq[i]);
    }
#pragma unroll
    for (int c = 0; c < 4; ++c) {
      float4 kv1 = *(const float4*)(k1p + 4*c);
      float4 kvf = *(const float4*)(kfp + 4*c);
      e1 += qv[4*c]*kv1.x + qv[4*c+1]*kv1.y + qv[4*c+2]*kv1.z + qv[4*c+3]*kv1.w;
      e2 += qv[4*c]*kvf.x + qv[4*c+1]*kvf.y + qv[4*c+2]*kvf.z + qv[4*c+3]*kvf.w;
    }
  }
  e1 += __shfl_xor(e1, 16, 64); e1 += __shfl_xor(e1, 32, 64);
  e2 += __shfl_xor(e2, 16, 64); e2 += __shfl_xor(e2, 32, 64);

#pragma unroll
  for (int r = 0; r < 4; ++r) {
    int row = 4*g + r;
    int src = (lane & 48) | row;
    float e1r = __shfl(e1, src, 64);
    float e2r = __shfl(e2, src, 64);
    float m_r = __shfl(m_run, src, 64);
    float l_r = __shfl(l_run, src, 64);
    float mnew = fmaxf(m_r, fmaxf(e1r, e2r));
    float alr = __expf(m_r - mnew);
    float w1  = __expf(e1r - mnew);
    float w2  = __expf(e2r - mnew);
    float linv = 1.f / (l_r*alr + w1 + w2);
    int qpos = (qt<<6) + wq0 + row;
    const float* v1p = cache_v + ((size_t)((B_ + b)*H_ + h)*Q_ + qpos)*HD_;
    const float* vfp = Y + (size_t)(b*Q_ + qpos)*QKVN_ + (H_*HD_ + KVH_*HD_) + (h/NREP_)*HD_;
    unsigned short* op = AOb + (size_t)(b*Q_ + qpos)*AOW_ + h*HD_;
#pragma unroll
    for (int db = 0; db < 4; ++db) {
      int d = db*16 + sub;
      float o = (acc_o[db][r]*alr + w1*v1p[d] + w2*vfp[d]) * linv;
      op[d] = f2b(o);
    }
  }
}

extern "C" void kernel_launch(void* const* d_in, const int* in_sizes, int n_in,
                              void* d_out, int out_size, void* d_ws, size_t ws_size,
                              hipStream_t stream) {
  const float* hidden  = (const float*)d_in[0];
  const float* Wq      = (const float*)d_in[1];
  const float* Wk      = (const float*)d_in[2];
  const float* Wv      = (const float*)d_in[3];
  const float* Wo      = (const float*)d_in[4];   // [HS][H*HD]
  const float* cache_k = (const float*)d_in[5];
  const float* cache_v = (const float*)d_in[6];
  const int*   pos_ids = (const int*)d_in[8];
  float* out = (float*)d_out;

  char* ws = (char*)d_ws;
  float* Y = (float*)ws;                                   // [2048][3072] fp32
  ws += (size_t)M_ * QKVN_ * 4;
  __hip_bfloat16* Xb  = (__hip_bfloat16*)ws;               // [2048][4096] bf16
  ws += (size_t)M_ * KIN_ * 2;
  __hip_bfloat16* Wb  = (__hip_bfloat16*)ws;               // [3072][4096] bf16
  ws += (size_t)QKVN_ * KIN_ * 2;
  __hip_bfloat16* Wob = (__hip_bfloat16*)ws;               // [2048][2048] bf16
  __hip_bfloat16* AOb = Xb;                                // Xb dead after QKV GEMM

  {
    long n;
    n = (long)M_ * KIN_;
    cast_f32_bf16<<<dim3((n/8 + 255)/256), 256, 0, stream>>>(hidden, Xb, n);
    n = (long)H_*HD_*KIN_;
    cast_f32_bf16<<<dim3((n/8 + 255)/256), 256, 0, stream>>>(Wq, Wb, n);
    n = (long)KVH_*HD_*KIN_;
    cast_f32_bf16<<<dim3((n/8 + 255)/256), 256, 0, stream>>>(Wk, Wb + (size_t)2048*KIN_, n);
    cast_f32_bf16<<<dim3((n/8 + 255)/256), 256, 0, stream>>>(Wv, Wb + (size_t)2560*KIN_, n);
    n = (long)HS_ * AOW_;
    cast_f32_bf16<<<dim3((n/8 + 255)/256), 256, 0, stream>>>(Wo, Wob, n);
  }

  // QKV: grid 48x16 = 768 blocks (3/CU)
  gemm_bf16_nt<<<dim3(QKVN_/64, M_/128), 256, 0, stream>>>(Xb, Wb, Y, KIN_, QKVN_);
  rope_kernel<<<dim3((M_*40*32 + 255)/256), 256, 0, stream>>>(Y, pos_ids);
  attn_mfma<<<dim3(1024), 256, 0, stream>>>(Y, cache_k, cache_v, (unsigned short*)AOb);
  // Wo: grid 32x16 = 512 blocks (2/CU)
  gemm_bf16_nt<<<dim3(HS_/64, M_/128), 256, 0, stream>>>(AOb, Wob, out, AOW_, HS_);
}

// Round 7
// 180.717 us; speedup vs baseline: 7.9547x; 1.0281x over previous
//
#include <hip/hip_runtime.h>
#include <hip/hip_bf16.h>
#include <math.h>

#define B_    2
#define Q_    1024
#define H_    32
#define KVH_  8
#define HD_   64
#define HS_   2048
#define NREP_ 4
#define KIN_  (2*HS_)            // 4096
#define M_    (B_*Q_)            // 2048
#define QKVN_ (H_*HD_ + 2*KVH_*HD_)  // 3072
#define AOW_  (H_*HD_)           // 2048
#define SCALE_ 0.125f            // 1/sqrt(64)

typedef __attribute__((ext_vector_type(8))) short bf16x8;
typedef __attribute__((ext_vector_type(4))) float f32x4;
typedef unsigned short u16;

static __device__ __forceinline__ u16 f2b(float f) {
  union { float f; unsigned int u; } c; c.f = f;
  unsigned int r = (c.u + 0x7fffu + ((c.u >> 16) & 1u)) >> 16;
  return (u16)r;
}
static __device__ __forceinline__ float b2f(u16 s) {
  union { unsigned int u; float f; } c;
  c.u = ((unsigned int)s) << 16;
  return c.f;
}
static __device__ __forceinline__ unsigned long long pack4s(float4 v, float sc) {
  return (unsigned long long)f2b(v.x*sc) |
         ((unsigned long long)f2b(v.y*sc) << 16) |
         ((unsigned long long)f2b(v.z*sc) << 32) |
         ((unsigned long long)f2b(v.w*sc) << 48);
}

#define GLOAD(SRC, DST) __builtin_amdgcn_global_load_lds( \
    (const __attribute__((address_space(1))) void*)(SRC), \
    (__attribute__((address_space(3))) void*)(DST), 16, 0, 0)

// ---------------- fp32 -> bf16 cast ----------------
__global__ __launch_bounds__(256) void cast_f32_bf16(
    const float* __restrict__ src, u16* __restrict__ dst, long n)
{
  long i = ((long)blockIdx.x * blockDim.x + threadIdx.x) * 8;
  if (i >= n) return;
  float4 a = *(const float4*)(src + i);
  float4 b = *(const float4*)(src + i + 4);
  unsigned long long o[2] = {pack4s(a, 1.f), pack4s(b, 1.f)};
  *(float4*)(dst + i) = *(const float4*)o;
}

// ---------------- cache K/V -> bf16 attn-ready swizzled layouts ----------------
// Kb  [bh][q][64]:  Kb[q][cc] = K0[q][cc ^ (q&7)]  (8-elem chunks)
// Vtb [bh][d][Q]:   Vtb[d][kt*64 + cc*8+j] = V0[kt*64 + (cc^(d&7))*8+j][d]
// grid (16 kt, 64 bh), 256 thr.
__global__ __launch_bounds__(256) void cast_kv(
    const float* __restrict__ k0, const float* __restrict__ v0,
    u16* __restrict__ Kb, u16* __restrict__ Vtb)
{
  __shared__ float Vs[64][65];
  const int kt = blockIdx.x, bh = blockIdx.y;
  const int t = threadIdx.x;
  const int r = t >> 2, seg = t & 3;

  // K: row r of tile, chunks 2seg, 2seg+1
  {
    const float* sp = k0 + ((size_t)bh*Q_ + (kt<<6) + r)*64;
    u16* dp = Kb + ((size_t)bh*Q_ + (kt<<6) + r)*64;
#pragma unroll
    for (int c2 = 2*seg; c2 < 2*seg+2; ++c2) {
      int ca = c2 ^ (r & 7);
      float4 a = *(const float4*)(sp + ca*8);
      float4 b = *(const float4*)(sp + ca*8 + 4);
      unsigned long long o[2] = {pack4s(a,1.f), pack4s(b,1.f)};
      *(float4*)(dp + c2*8) = *(const float4*)o;
    }
  }
  // V: tile to LDS, then transposed swizzled rows out
  {
    const float* sp = v0 + ((size_t)bh*Q_ + (kt<<6) + r)*64 + seg*16;
#pragma unroll
    for (int c = 0; c < 4; ++c) {
      float4 v = *(const float4*)(sp + 4*c);
      Vs[r][seg*16 + 4*c + 0] = v.x; Vs[r][seg*16 + 4*c + 1] = v.y;
      Vs[r][seg*16 + 4*c + 2] = v.z; Vs[r][seg*16 + 4*c + 3] = v.w;
    }
  }
  __syncthreads();
  {
    const int d = r;
    u16* dp = Vtb + ((size_t)bh*64 + d)*Q_ + (kt<<6);
#pragma unroll
    for (int c2 = 2*seg; c2 < 2*seg+2; ++c2) {
      int ca = c2 ^ (d & 7);
      u16 o[8];
#pragma unroll
      for (int j = 0; j < 8; ++j) o[j] = f2b(Vs[ca*8 + j][d]);
      *(float4*)(dp + c2*8) = *(const float4*)o;
    }
  }
}

// ---------------- bf16 NT MFMA GEMM, 128x64, BK=64, dbuf + counted vmcnt ----------------
// C[m][n] = sum_k A[m][k]*W[n][k].  Templated output dtype (bf16 or fp32).
template<bool OUT_BF16>
__global__ __launch_bounds__(256, 3) void gemm_nt(
    const u16* __restrict__ A, const u16* __restrict__ W,
    void* __restrict__ Cv, int K, int ldc)
{
  __shared__ u16 As[2*128*64];   // 2 x 16 KB
  __shared__ u16 Bs[2*64*64];    // 2 x 8 KB
  const int m0 = blockIdx.y << 7, n0 = blockIdx.x << 6;
  const int t = threadIdx.x;
  const int wave = t >> 6, lane = t & 63;
  const int wr = wave >> 1, wc = wave & 1;

  f32x4 acc[4][2] = {};

  const int lrow8 = lane >> 3;                 // 0..7
  const int lcsw  = ((lane & 7) ^ lrow8) * 8;  // pre-swizzled source chunk
  const int fr    = lane & 15;
  const int g     = lane >> 4;

#define GEMM_STAGE(BUF, K0) do { \
    _Pragma("unroll") \
    for (int p = 0; p < 4; ++p) { \
      int rbase = p * 32 + wave * 8; \
      GLOAD(A + (size_t)(m0 + rbase + lrow8) * K + (K0) + lcsw, \
            As + (BUF)*8192 + rbase * 64); \
    } \
    _Pragma("unroll") \
    for (int p = 0; p < 2; ++p) { \
      int rbase = p * 32 + wave * 8; \
      GLOAD(W + (size_t)(n0 + rbase + lrow8) * K + (K0) + lcsw, \
            Bs + (BUF)*4096 + rbase * 64); \
    } \
  } while(0)

  GEMM_STAGE(0, 0);
  int cur = 0;
  for (int k0 = 0; k0 < K; k0 += 64) {
    if (k0 + 64 < K) {
      GEMM_STAGE(cur ^ 1, k0 + 64);
      asm volatile("s_waitcnt vmcnt(6)" ::: "memory");
    } else {
      asm volatile("s_waitcnt vmcnt(0)" ::: "memory");
    }
    asm volatile("s_barrier" ::: "memory");

    const u16* Ab = As + cur*8192;
    const u16* Bb = Bs + cur*4096;
    bf16x8 af[4][2], bfr[2][2];
#pragma unroll
    for (int kk = 0; kk < 2; ++kk) {
      int ck = kk * 4 + g;
#pragma unroll
      for (int mi = 0; mi < 4; ++mi) {
        int row = wr * 64 + mi * 16 + fr;
        af[mi][kk] = *(const bf16x8*)(Ab + row * 64 + ((ck ^ (row & 7)) << 3));
      }
#pragma unroll
      for (int ni = 0; ni < 2; ++ni) {
        int row = wc * 32 + ni * 16 + fr;
        bfr[ni][kk] = *(const bf16x8*)(Bb + row * 64 + ((ck ^ (row & 7)) << 3));
      }
    }
    __builtin_amdgcn_s_setprio(1);
#pragma unroll
    for (int kk = 0; kk < 2; ++kk)
#pragma unroll
      for (int mi = 0; mi < 4; ++mi)
#pragma unroll
        for (int ni = 0; ni < 2; ++ni)
          acc[mi][ni] = __builtin_amdgcn_mfma_f32_16x16x32_bf16(af[mi][kk], bfr[ni][kk], acc[mi][ni], 0, 0, 0);
    __builtin_amdgcn_s_setprio(0);
    asm volatile("s_barrier" ::: "memory");
    cur ^= 1;
  }
#undef GEMM_STAGE

#pragma unroll
  for (int mi = 0; mi < 4; ++mi) {
    int rbase = m0 + wr * 64 + mi * 16 + (lane >> 4) * 4;
#pragma unroll
    for (int ni = 0; ni < 2; ++ni) {
      int col = n0 + wc * 32 + ni * 16 + (lane & 15);
#pragma unroll
      for (int r = 0; r < 4; ++r) {
        if (OUT_BF16) ((u16*)Cv)[(size_t)(rbase + r) * ldc + col] = f2b(acc[mi][ni][r]);
        else          ((float*)Cv)[(size_t)(rbase + r) * ldc + col] = acc[mi][ni][r];
      }
    }
  }
}

// ---------------- RoPE on bf16 Y, q pre-scaled by 1/8 ----------------
__global__ void rope_kernel(u16* __restrict__ Yb, const int* __restrict__ pos_ids)
{
  int idx = blockIdx.x * blockDim.x + threadIdx.x;   // 8 pairs each
  const int nwork = M_ * 40 * 4;
  if (idx >= nwork) return;
  int dblk = idx & 3;
  int hr   = idx >> 2;
  int head = hr % 40;
  int m    = hr / 40;
  u16* row = Yb + (size_t)m * QKVN_ + head * 64;
  int d0 = dblk * 8;
  float4 lo4 = *(const float4*)(row + d0);
  float4 hi4 = *(const float4*)(row + d0 + 32);
  const u16* lo = (const u16*)&lo4;
  const u16* hi = (const u16*)&hi4;
  float p = (float)(pos_ids[m] + 2);
  float qs = (head < 32) ? SCALE_ : 1.0f;
  u16 olo[8], ohi[8];
#pragma unroll
  for (int i = 0; i < 8; ++i) {
    int d = d0 + i;
    float inv = exp2f(-0.4152410118609203f * (float)d);
    float f = p * inv;
    float c, s;
    sincosf(f, &s, &c);
    float x0 = b2f(lo[i]), x1 = b2f(hi[i]);
    olo[i] = f2b((x0*c - x1*s) * qs);
    ohi[i] = f2b((x1*c + x0*s) * qs);
  }
  *(float4*)(row + d0)      = *(const float4*)olo;
  *(float4*)(row + d0 + 32) = *(const float4*)ohi;
}

// ---------------- MFMA flash attention: DMA-staged bf16 K/V, dbuf, balanced qt ----------------
__global__ __launch_bounds__(256, 3) void attn_mfma(
    const u16* __restrict__ Yb,         // [M_][3072] bf16, rope applied, q scaled
    const u16* __restrict__ Kb,         // [bh][Q][64] swizzled bf16
    const u16* __restrict__ Vtb,        // [bh][64][Q] swizzled bf16
    const float* __restrict__ cache_k,  // [2][B][H][Q][64] fp32 (tail entry 1)
    const float* __restrict__ cache_v,
    u16* __restrict__ AOb)              // [M_][2048] bf16
{
  __shared__ u16 Qs[64*64];
  __shared__ u16 Ps[64*64];
  __shared__ u16 Ks[2*64*64];
  __shared__ u16 Vt[2*64*64];

  const int bid = blockIdx.x;
  const int xcd = bid & 7, within = bid >> 3;
  const int w16 = within & 15;
  const int qt = (w16 & 1) ? (15 - (w16 >> 1)) : (w16 >> 1);   // balanced order
  const int pair = xcd * 8 + (within >> 4);
  const int h = pair >> 1, b = pair & 1;
  const int bh = b * H_ + h;

  const int t = threadIdx.x;
  const int wave = t >> 6, lane = t & 63;
  const int g = lane >> 4, sub = lane & 15;
  const int wq0 = wave * 16;
  const int srow = (lane >> 3);        // 0..7 staging row within 8-stripe
  const int scc  = lane & 7;           // staging chunk

  const u16* KbT = Kb + (size_t)bh * Q_ * 64;
  const u16* VtT = Vtb + (size_t)bh * 64 * Q_;

#define ATTN_STAGE(BUF, KT) do { \
    _Pragma("unroll") \
    for (int p = 0; p < 2; ++p) { \
      int r = p*32 + wave*8 + srow; \
      GLOAD(KbT + (size_t)(((KT)<<6) + r)*64 + scc*8, Ks + (BUF)*4096 + p*2048 + wave*512); \
      GLOAD(VtT + (size_t)r*Q_ + ((KT)<<6) + scc*8,   Vt + (BUF)*4096 + p*2048 + wave*512); \
    } \
  } while(0)

  // Q stage via DMA (source pre-swizzled per-lane)
  {
#pragma unroll
    for (int p = 0; p < 2; ++p) {
      int r = p*32 + wave*8 + srow;
      GLOAD(Yb + (size_t)(b*Q_ + (qt<<6) + r)*QKVN_ + h*64 + ((scc ^ (r&7))<<3),
            Qs + p*2048 + wave*512);
    }
  }
  ATTN_STAGE(0, 0);
  asm volatile("s_waitcnt vmcnt(4)" ::: "memory");   // Q done, stage0 in flight
  asm volatile("s_barrier" ::: "memory");

  bf16x8 qb[2];
#pragma unroll
  for (int kk = 0; kk < 2; ++kk) {
    int row = wq0 + sub;
    qb[kk] = *(const bf16x8*)&Qs[row*64 + (((4*kk+g) ^ (row&7))<<3)];
  }

  float m_run = -3e38f, l_run = 0.f;
  f32x4 acc_o[4] = {};
  int cur = 0;

  for (int kt = 0; kt <= qt; ++kt) {
    if (kt < qt) {
      ATTN_STAGE(cur ^ 1, kt + 1);
      asm volatile("s_waitcnt vmcnt(4)" ::: "memory");
    } else {
      asm volatile("s_waitcnt vmcnt(0)" ::: "memory");
    }
    asm volatile("s_barrier" ::: "memory");

    const u16* ksb = Ks + cur*4096;
    const u16* vtb = Vt + cur*4096;

    // ---- S^T = K Q^T ----
    f32x4 s[4] = {};
    __builtin_amdgcn_s_setprio(1);
#pragma unroll
    for (int kk = 0; kk < 2; ++kk) {
      int kb = 4*kk + g;
#pragma unroll
      for (int cb = 0; cb < 4; ++cb) {
        int krow = cb*16 + sub;
        bf16x8 kf = *(const bf16x8*)&ksb[krow*64 + ((kb ^ (krow&7))<<3)];
        s[cb] = __builtin_amdgcn_mfma_f32_16x16x32_bf16(kf, qb[kk], s[cb], 0, 0, 0);
      }
    }
    __builtin_amdgcn_s_setprio(0);

    if (kt == qt) {  // causal mask
#pragma unroll
      for (int cb = 0; cb < 4; ++cb)
#pragma unroll
        for (int r = 0; r < 4; ++r)
          if (cb*16 + 4*g + r > wq0 + sub) s[cb][r] = -3e38f;
    }

    // ---- online softmax, lane owns q = wq0+sub ----
    float mt = -3e38f;
#pragma unroll
    for (int cb = 0; cb < 4; ++cb)
#pragma unroll
      for (int r = 0; r < 4; ++r) mt = fmaxf(mt, s[cb][r]);
    mt = fmaxf(mt, __shfl_xor(mt, 16, 64));
    mt = fmaxf(mt, __shfl_xor(mt, 32, 64));

    float al = 1.0f;
    if (__any(mt > m_run + 8.f)) {       // T13 defer-max
      float mnew = fmaxf(m_run, mt);
      al = __expf(m_run - mnew);
      m_run = mnew;
      int base = (lane & 48) + ((lane & 48) >> 2);
#pragma unroll
      for (int r = 0; r < 4; ++r) {
        float alr = __shfl(al, base + r, 64);
#pragma unroll
        for (int db = 0; db < 4; ++db) acc_o[db][r] *= alr;
      }
    }

    float sum = 0.f;
#pragma unroll
    for (int cb = 0; cb < 4; ++cb) {
      float p0 = __expf(s[cb][0]-m_run), p1 = __expf(s[cb][1]-m_run);
      float p2 = __expf(s[cb][2]-m_run), p3 = __expf(s[cb][3]-m_run);
      sum += (p0+p1)+(p2+p3);
      unsigned long long pk =
          (unsigned long long)((unsigned int)f2b(p0) | ((unsigned int)f2b(p1)<<16)) |
          ((unsigned long long)((unsigned int)f2b(p2) | ((unsigned int)f2b(p3)<<16)) << 32);
      int col8 = cb*2 + (g>>1);
      int dst = (wq0 + sub)*64 + ((col8 ^ (sub&7))<<3) + ((g&1)<<2);
      *(unsigned long long*)&Ps[dst] = pk;
    }
    sum += __shfl_xor(sum, 16, 64);
    sum += __shfl_xor(sum, 32, 64);
    l_run = l_run*al + sum;

    // ---- O += P V ----
    __builtin_amdgcn_s_setprio(1);
#pragma unroll
    for (int kk = 0; kk < 2; ++kk) {
      bf16x8 pa = *(const bf16x8*)&Ps[(wq0 + sub)*64 + (((4*kk+g) ^ (sub&7))<<3)];
#pragma unroll
      for (int db = 0; db < 4; ++db) {
        int drow = db*16 + sub;
        bf16x8 vf = *(const bf16x8*)&vtb[drow*64 + (((4*kk+g) ^ (drow&7))<<3)];
        acc_o[db] = __builtin_amdgcn_mfma_f32_16x16x32_bf16(pa, vf, acc_o[db], 0, 0, 0);
      }
    }
    __builtin_amdgcn_s_setprio(0);
    asm volatile("s_barrier" ::: "memory");
    cur ^= 1;
  }
#undef ATTN_STAGE

  // ---- tail: 2 extra keys (cache[1] diag fp32, fresh k/v from Yb bf16) ----
  const int qrow_mine = wq0 + sub;
  const int qpos_mine = (qt<<6) + qrow_mine;
  float e1 = 0.f, e2 = 0.f;
  {
    const float* k1p = cache_k + ((size_t)((B_ + b)*H_ + h)*Q_ + qpos_mine)*HD_ + g*16;
    const u16*   kfp = Yb + (size_t)(b*Q_ + qpos_mine)*QKVN_ + H_*HD_ + (h/NREP_)*HD_ + g*16;
    float qv[16];
#pragma unroll
    for (int half = 0; half < 2; ++half) {
      int kb = 2*g + half;
      bf16x8 qq = *(const bf16x8*)&Qs[qrow_mine*64 + ((kb ^ (qrow_mine&7))<<3)];
#pragma unroll
      for (int i = 0; i < 8; ++i) qv[half*8 + i] = b2f(((u16)qq[i]));
    }
    float4 kf4a = *(const float4*)kfp;         // 8 bf16
    float4 kf4b = *(const float4*)(kfp + 8);
    const u16* kf16a = (const u16*)&kf4a;
    const u16* kf16b = (const u16*)&kf4b;
#pragma unroll
    for (int c = 0; c < 4; ++c) {
      float4 kv1 = *(const float4*)(k1p + 4*c);
      e1 += qv[4*c]*kv1.x + qv[4*c+1]*kv1.y + qv[4*c+2]*kv1.z + qv[4*c+3]*kv1.w;
    }
#pragma unroll
    for (int i = 0; i < 8; ++i) {
      e2 += qv[i]   * b2f(kf16a[i]);
      e2 += qv[8+i] * b2f(kf16b[i]);
    }
  }
  e1 += __shfl_xor(e1, 16, 64); e1 += __shfl_xor(e1, 32, 64);
  e2 += __shfl_xor(e2, 16, 64); e2 += __shfl_xor(e2, 32, 64);

#pragma unroll
  for (int r = 0; r < 4; ++r) {
    int row = 4*g + r;
    int src = (lane & 48) | row;
    float e1r = __shfl(e1, src, 64);
    float e2r = __shfl(e2, src, 64);
    float m_r = __shfl(m_run, src, 64);
    float l_r = __shfl(l_run, src, 64);
    float mnew = fmaxf(m_r, fmaxf(e1r, e2r));
    float alr = __expf(m_r - mnew);
    float w1  = __expf(e1r - mnew);
    float w2  = __expf(e2r - mnew);
    float linv = 1.f / (l_r*alr + w1 + w2);
    int qpos = (qt<<6) + wq0 + row;
    const float* v1p = cache_v + ((size_t)((B_ + b)*H_ + h)*Q_ + qpos)*HD_;
    const u16*   vfp = Yb + (size_t)(b*Q_ + qpos)*QKVN_ + (H_*HD_ + KVH_*HD_) + (h/NREP_)*HD_;
    u16* op = AOb + (size_t)(b*Q_ + qpos)*AOW_ + h*HD_;
#pragma unroll
    for (int db = 0; db < 4; ++db) {
      int d = db*16 + sub;
      float o = (acc_o[db][r]*alr + w1*v1p[d] + w2*b2f(vfp[d])) * linv;
      op[d] = f2b(o);
    }
  }
}

extern "C" void kernel_launch(void* const* d_in, const int* in_sizes, int n_in,
                              void* d_out, int out_size, void* d_ws, size_t ws_size,
                              hipStream_t stream) {
  const float* hidden  = (const float*)d_in[0];
  const float* Wq      = (const float*)d_in[1];
  const float* Wk      = (const float*)d_in[2];
  const float* Wv      = (const float*)d_in[3];
  const float* Wo      = (const float*)d_in[4];   // [HS][H*HD]
  const float* cache_k = (const float*)d_in[5];
  const float* cache_v = (const float*)d_in[6];
  const int*   pos_ids = (const int*)d_in[8];
  float* out = (float*)d_out;

  char* ws = (char*)d_ws;
  u16* Yb  = (u16*)ws;  ws += (size_t)M_ * QKVN_ * 2;      // 12.6 MB
  u16* Xb  = (u16*)ws;  ws += (size_t)M_ * KIN_ * 2;       // 16.8 MB
  u16* Wb  = (u16*)ws;  ws += (size_t)QKVN_ * KIN_ * 2;    // 25.2 MB
  u16* Wob = (u16*)ws;  ws += (size_t)HS_ * AOW_ * 2;      // 8.4 MB
  u16* Kb  = (u16*)ws;  ws += (size_t)B_*H_*Q_*64 * 2;     // 8.4 MB
  u16* Vtb = (u16*)ws;  ws += (size_t)B_*H_*Q_*64 * 2;     // 8.4 MB
  u16* AOb = Xb;                                           // Xb dead after QKV GEMM

  {
    long n;
    n = (long)M_ * KIN_;
    cast_f32_bf16<<<dim3((n/8 + 255)/256), 256, 0, stream>>>(hidden, Xb, n);
    n = (long)H_*HD_*KIN_;
    cast_f32_bf16<<<dim3((n/8 + 255)/256), 256, 0, stream>>>(Wq, Wb, n);
    n = (long)KVH_*HD_*KIN_;
    cast_f32_bf16<<<dim3((n/8 + 255)/256), 256, 0, stream>>>(Wk, Wb + (size_t)2048*KIN_, n);
    cast_f32_bf16<<<dim3((n/8 + 255)/256), 256, 0, stream>>>(Wv, Wb + (size_t)2560*KIN_, n);
    n = (long)HS_ * AOW_;
    cast_f32_bf16<<<dim3((n/8 + 255)/256), 256, 0, stream>>>(Wo, Wob, n);
  }
  cast_kv<<<dim3(16, 64), 256, 0, stream>>>(cache_k, cache_v, Kb, Vtb);

  // QKV: grid 48x16 = 768 blocks (3/CU), bf16 out
  gemm_nt<true><<<dim3(QKVN_/64, M_/128), 256, 0, stream>>>(Xb, Wb, (void*)Yb, KIN_, QKVN_);
  rope_kernel<<<dim3((M_*40*4 + 255)/256), 256, 0, stream>>>(Yb, pos_ids);
  attn_mfma<<<dim3(1024), 256, 0, stream>>>(Yb, Kb, Vtb, cache_k, cache_v, AOb);
  // Wo: grid 32x16 = 512 blocks, fp32 out
  gemm_nt<false><<<dim3(HS_/64, M_/128), 256, 0, stream>>>(AOb, Wob, (void*)out, AOW_, HS_);
}

// Round 9
// 168.332 us; speedup vs baseline: 8.5399x; 1.0736x over previous
//
#include <hip/hip_runtime.h>
#include <hip/hip_bf16.h>
#include <math.h>

#define B_    2
#define Q_    1024
#define H_    32
#define KVH_  8
#define HD_   64
#define HS_   2048
#define NREP_ 4
#define KIN_  (2*HS_)            // 4096
#define M_    (B_*Q_)            // 2048
#define QKVN_ (H_*HD_ + 2*KVH_*HD_)  // 3072
#define AOW_  (H_*HD_)           // 2048
#define SCALE_ 0.125f            // 1/sqrt(64)

typedef __attribute__((ext_vector_type(8))) short bf16x8;
typedef __attribute__((ext_vector_type(4))) float f32x4;
typedef unsigned short u16;

static __device__ __forceinline__ u16 f2b(float f) {
  union { float f; unsigned int u; } c; c.f = f;
  unsigned int r = (c.u + 0x7fffu + ((c.u >> 16) & 1u)) >> 16;
  return (u16)r;
}
static __device__ __forceinline__ float b2f(u16 s) {
  union { unsigned int u; float f; } c;
  c.u = ((unsigned int)s) << 16;
  return c.f;
}
static __device__ __forceinline__ unsigned long long pack4s(float4 v, float sc) {
  return (unsigned long long)f2b(v.x*sc) |
         ((unsigned long long)f2b(v.y*sc) << 16) |
         ((unsigned long long)f2b(v.z*sc) << 32) |
         ((unsigned long long)f2b(v.w*sc) << 48);
}

#define GLOAD(SRC, DST) __builtin_amdgcn_global_load_lds( \
    (const __attribute__((address_space(1))) void*)(SRC), \
    (__attribute__((address_space(3))) void*)(DST), 16, 0, 0)

// ---------------- ONE merged fp32->bf16 cast over all 5 inputs ----------------
__global__ __launch_bounds__(256) void cast_all(
    const float* __restrict__ hidden, const float* __restrict__ Wq,
    const float* __restrict__ Wk, const float* __restrict__ Wv,
    const float* __restrict__ Wo,
    u16* __restrict__ Xb, u16* __restrict__ Wb, u16* __restrict__ Wob)
{
  const int U0 = 1048576;            // X      (2048*4096/8)
  const int U1 = U0 + 1048576;       // +Wq
  const int U2 = U1 + 262144;        // +Wk    (512*4096/8)
  const int U3 = U2 + 262144;        // +Wv
  const int U4 = U3 + 524288;        // +Wo    (2048*2048/8)
  for (int u = blockIdx.x*blockDim.x + threadIdx.x; u < U4; u += gridDim.x*blockDim.x) {
    const float* src; u16* dst;
    if (u < U0)      { src = hidden + (size_t)u*8;   dst = Xb + (size_t)u*8; }
    else if (u < U1) { src = Wq + (size_t)(u-U0)*8;  dst = Wb + (size_t)(u-U0)*8; }
    else if (u < U2) { src = Wk + (size_t)(u-U1)*8;  dst = Wb + (size_t)2048*KIN_ + (size_t)(u-U1)*8; }
    else if (u < U3) { src = Wv + (size_t)(u-U2)*8;  dst = Wb + (size_t)2560*KIN_ + (size_t)(u-U2)*8; }
    else             { src = Wo + (size_t)(u-U3)*8;  dst = Wob + (size_t)(u-U3)*8; }
    float4 a = *(const float4*)src;
    float4 bb = *(const float4*)(src + 4);
    unsigned long long o[2] = {pack4s(a, 1.f), pack4s(bb, 1.f)};
    *(float4*)dst = *(const float4*)o;
  }
}

// ---------------- cache K/V -> bf16 attn-ready swizzled layouts ----------------
__global__ __launch_bounds__(256) void cast_kv(
    const float* __restrict__ k0, const float* __restrict__ v0,
    u16* __restrict__ Kb, u16* __restrict__ Vtb)
{
  __shared__ float Vs[64][65];
  const int kt = blockIdx.x, bh = blockIdx.y;
  const int t = threadIdx.x;
  const int r = t >> 2, seg = t & 3;
  {
    const float* sp = k0 + ((size_t)bh*Q_ + (kt<<6) + r)*64;
    u16* dp = Kb + ((size_t)bh*Q_ + (kt<<6) + r)*64;
#pragma unroll
    for (int c2 = 2*seg; c2 < 2*seg+2; ++c2) {
      int ca = c2 ^ (r & 7);
      float4 a = *(const float4*)(sp + ca*8);
      float4 b = *(const float4*)(sp + ca*8 + 4);
      unsigned long long o[2] = {pack4s(a,1.f), pack4s(b,1.f)};
      *(float4*)(dp + c2*8) = *(const float4*)o;
    }
  }
  {
    const float* sp = v0 + ((size_t)bh*Q_ + (kt<<6) + r)*64 + seg*16;
#pragma unroll
    for (int c = 0; c < 4; ++c) {
      float4 v = *(const float4*)(sp + 4*c);
      Vs[r][seg*16 + 4*c + 0] = v.x; Vs[r][seg*16 + 4*c + 1] = v.y;
      Vs[r][seg*16 + 4*c + 2] = v.z; Vs[r][seg*16 + 4*c + 3] = v.w;
    }
  }
  __syncthreads();
  {
    const int d = r;
    u16* dp = Vtb + ((size_t)bh*64 + d)*Q_ + (kt<<6);
#pragma unroll
    for (int c2 = 2*seg; c2 < 2*seg+2; ++c2) {
      int ca = c2 ^ (d & 7);
      u16 o[8];
#pragma unroll
      for (int j = 0; j < 8; ++j) o[j] = f2b(Vs[ca*8 + j][d]);
      *(float4*)(dp + c2*8) = *(const float4*)o;
    }
  }
}

// ---------------- bf16 NT MFMA GEMM, 128x64, BK=64, dbuf; QKV mode fuses RoPE ----------------
template<bool QKV>
__global__ __launch_bounds__(256, 3) void gemm_nt(
    const u16* __restrict__ A, const u16* __restrict__ W,
    void* __restrict__ Cv, int K, int ldc, const int* __restrict__ pos_ids)
{
  __shared__ u16 As[2*128*64];   // 32 KB (reused as fp32 exchange in epilogue)
  __shared__ u16 Bs[2*64*64];    // 16 KB
  const int m0 = blockIdx.y << 7, n0 = blockIdx.x << 6;
  const int t = threadIdx.x;
  const int wave = t >> 6, lane = t & 63;
  const int wr = wave >> 1, wc = wave & 1;

  f32x4 acc[4][2] = {};

  const int lrow8 = lane >> 3;
  const int lcsw  = ((lane & 7) ^ lrow8) * 8;
  const int fr    = lane & 15;
  const int g     = lane >> 4;

#define GEMM_STAGE(BUF, K0) do { \
    _Pragma("unroll") \
    for (int p = 0; p < 4; ++p) { \
      int rbase = p * 32 + wave * 8; \
      GLOAD(A + (size_t)(m0 + rbase + lrow8) * K + (K0) + lcsw, \
            As + (BUF)*8192 + rbase * 64); \
    } \
    _Pragma("unroll") \
    for (int p = 0; p < 2; ++p) { \
      int rbase = p * 32 + wave * 8; \
      GLOAD(W + (size_t)(n0 + rbase + lrow8) * K + (K0) + lcsw, \
            Bs + (BUF)*4096 + rbase * 64); \
    } \
  } while(0)

  GEMM_STAGE(0, 0);
  int cur = 0;
  for (int k0 = 0; k0 < K; k0 += 64) {
    if (k0 + 64 < K) {
      GEMM_STAGE(cur ^ 1, k0 + 64);
      asm volatile("s_waitcnt vmcnt(6)" ::: "memory");
    } else {
      asm volatile("s_waitcnt vmcnt(0)" ::: "memory");
    }
    asm volatile("s_barrier" ::: "memory");

    const u16* Ab = As + cur*8192;
    const u16* Bb = Bs + cur*4096;
    bf16x8 af[4][2], bfr[2][2];
#pragma unroll
    for (int kk = 0; kk < 2; ++kk) {
      int ck = kk * 4 + g;
#pragma unroll
      for (int mi = 0; mi < 4; ++mi) {
        int row = wr * 64 + mi * 16 + fr;
        af[mi][kk] = *(const bf16x8*)(Ab + row * 64 + ((ck ^ (row & 7)) << 3));
      }
#pragma unroll
      for (int ni = 0; ni < 2; ++ni) {
        int row = wc * 32 + ni * 16 + fr;
        bfr[ni][kk] = *(const bf16x8*)(Bb + row * 64 + ((ck ^ (row & 7)) << 3));
      }
    }
    __builtin_amdgcn_s_setprio(1);
#pragma unroll
    for (int kk = 0; kk < 2; ++kk)
#pragma unroll
      for (int mi = 0; mi < 4; ++mi)
#pragma unroll
        for (int ni = 0; ni < 2; ++ni)
          acc[mi][ni] = __builtin_amdgcn_mfma_f32_16x16x32_bf16(af[mi][kk], bfr[ni][kk], acc[mi][ni], 0, 0, 0);
    __builtin_amdgcn_s_setprio(0);
    asm volatile("s_barrier" ::: "memory");
    cur ^= 1;
  }
#undef GEMM_STAGE

  if (QKV && n0 < 2560) {
    // ---- fused RoPE epilogue: pair (d, d+32) exchange via LDS, fp32 ----
    float* xch = (float*)As;   // 128 x 64 fp32 = 32 KB
    __syncthreads();
#pragma unroll
    for (int mi = 0; mi < 4; ++mi)
#pragma unroll
      for (int ni = 0; ni < 2; ++ni)
#pragma unroll
        for (int r = 0; r < 4; ++r)
          xch[(wr*64 + mi*16 + g*4 + r)*64 + wc*32 + ni*16 + (lane & 15)] = acc[mi][ni][r];
    __syncthreads();
    const bool isq = (n0 < 2048);
    u16* outp = (u16*)Cv;
#pragma unroll
    for (int mi = 0; mi < 4; ++mi) {
#pragma unroll
      for (int r = 0; r < 4; ++r) {
        int rl = wr*64 + mi*16 + g*4 + r;
        int m = m0 + rl;
        float p = (float)(pos_ids[m] + 2);
#pragma unroll
        for (int ni = 0; ni < 2; ++ni) {
          int dr = ni*16 + (lane & 15);              // freq index 0..31
          float inv = exp2f(-0.4152410118609203f * (float)dr);
          float f = p * inv;
          float c, s;
          sincosf(f, &s, &c);
          float mine = acc[mi][ni][r];
          float part = xch[rl*64 + ((wc^1)*32 + ni*16 + (lane & 15))];
          float outv = (wc == 0) ? (mine*c - part*s) : (mine*c + part*s);
          if (isq) outv *= SCALE_;
          outp[(size_t)m * ldc + n0 + wc*32 + ni*16 + (lane & 15)] = f2b(outv);
        }
      }
    }
  } else {
#pragma unroll
    for (int mi = 0; mi < 4; ++mi) {
      int rbase = m0 + wr * 64 + mi * 16 + g * 4;
#pragma unroll
      for (int ni = 0; ni < 2; ++ni) {
        int col = n0 + wc * 32 + ni * 16 + (lane & 15);
#pragma unroll
        for (int r = 0; r < 4; ++r) {
          if (QKV) ((u16*)Cv)[(size_t)(rbase + r) * ldc + col] = f2b(acc[mi][ni][r]);
          else     ((float*)Cv)[(size_t)(rbase + r) * ldc + col] = acc[mi][ni][r];
        }
      }
    }
  }
}

// ---------------- MFMA flash attention: QBLK=128, 8 waves, DMA K/V, dbuf ----------------
__global__ __launch_bounds__(512, 4) void attn_mfma(
    const u16* __restrict__ Yb,         // [M_][3072] bf16, rope applied, q scaled
    const u16* __restrict__ Kb,         // [bh][Q][64] swizzled bf16
    const u16* __restrict__ Vtb,        // [bh][64][Q] swizzled bf16
    const float* __restrict__ cache_k,  // [2][B][H][Q][64] fp32
    const float* __restrict__ cache_v,
    u16* __restrict__ AOb)              // [M_][2048] bf16
{
  __shared__ u16 Qs[128*64];   // 16 KB
  __shared__ u16 Ps[128*64];   // 16 KB
  __shared__ u16 Ks[2*64*64];  // 16 KB
  __shared__ u16 Vt[2*64*64];  // 16 KB  (total 64 KB)

  const int bid = blockIdx.x;
  const int xcd = bid & 7, within = bid >> 3;
  const int w8 = within & 7;
  const int qtb = (w8 & 1) ? (7 - (w8 >> 1)) : (w8 >> 1);   // balanced order
  const int pair = xcd * 8 + (within >> 3);
  const int h = pair >> 1, b = pair & 1;
  const int bh = b * H_ + h;

  const int t = threadIdx.x;
  const int wave = t >> 6, lane = t & 63;
  const int g = lane >> 4, sub = lane & 15;
  const int wq0 = wave * 16;                 // 0..112
  const int srow = lane >> 3;                // 0..7
  const int scc  = lane & 7;

  const u16* KbT = Kb + (size_t)bh * Q_ * 64;
  const u16* VtT = Vtb + (size_t)bh * 64 * Q_;

#define ATTN_STAGE(BUF, KT) do { \
    int r_ = wave*8 + srow; \
    GLOAD(KbT + (size_t)(((KT)<<6) + r_)*64 + scc*8, Ks + (BUF)*4096 + wave*512); \
    GLOAD(VtT + (size_t)r_*Q_ + ((KT)<<6) + scc*8,   Vt + (BUF)*4096 + wave*512); \
  } while(0)

  // stage Q (128 rows, 2 rounds), swizzled at source
  {
#pragma unroll
    for (int p = 0; p < 2; ++p) {
      int r = p*64 + wave*8 + srow;
      GLOAD(Yb + (size_t)(b*Q_ + qtb*128 + r)*QKVN_ + h*64 + ((scc ^ (r&7))<<3),
            Qs + p*4096 + wave*512);
    }
  }
  ATTN_STAGE(0, 0);
  asm volatile("s_waitcnt vmcnt(2)" ::: "memory");   // Q landed; stage0 in flight
  asm volatile("s_barrier" ::: "memory");

  bf16x8 qb[2];
#pragma unroll
  for (int kk = 0; kk < 2; ++kk) {
    int row = wq0 + sub;
    qb[kk] = *(const bf16x8*)&Qs[row*64 + (((4*kk+g) ^ (row&7))<<3)];
  }

  float m_run = -3e38f, l_run = 0.f;
  f32x4 acc_o[4] = {};
  int cur = 0;
  const int nkt = 2*qtb + 2;

  for (int kt = 0; kt < nkt; ++kt) {
    if (kt + 1 < nkt) {
      ATTN_STAGE(cur ^ 1, kt + 1);
      asm volatile("s_waitcnt vmcnt(2)" ::: "memory");
    } else {
      asm volatile("s_waitcnt vmcnt(0)" ::: "memory");
    }
    asm volatile("s_barrier" ::: "memory");

    // wave-uniform skip of fully-masked tiles (causal)
    if (kt*64 <= qtb*128 + wq0 + 15) {
      const u16* ksb = Ks + cur*4096;
      const u16* vtb = Vt + cur*4096;

      f32x4 s[4] = {};
      __builtin_amdgcn_s_setprio(1);
#pragma unroll
      for (int kk = 0; kk < 2; ++kk) {
        int kb = 4*kk + g;
#pragma unroll
        for (int cb = 0; cb < 4; ++cb) {
          int krow = cb*16 + sub;
          bf16x8 kf = *(const bf16x8*)&ksb[krow*64 + ((kb ^ (krow&7))<<3)];
          s[cb] = __builtin_amdgcn_mfma_f32_16x16x32_bf16(kf, qb[kk], s[cb], 0, 0, 0);
        }
      }
      __builtin_amdgcn_s_setprio(0);

      if (kt >= 2*qtb) {   // diagonal region: apply causal mask
#pragma unroll
        for (int cb = 0; cb < 4; ++cb)
#pragma unroll
          for (int r = 0; r < 4; ++r)
            if (kt*64 + cb*16 + 4*g + r > qtb*128 + wq0 + sub) s[cb][r] = -3e38f;
      }

      float mt = -3e38f;
#pragma unroll
      for (int cb = 0; cb < 4; ++cb)
#pragma unroll
        for (int r = 0; r < 4; ++r) mt = fmaxf(mt, s[cb][r]);
      mt = fmaxf(mt, __shfl_xor(mt, 16, 64));
      mt = fmaxf(mt, __shfl_xor(mt, 32, 64));

      float al = 1.0f;
      if (__any(mt > m_run + 8.f)) {       // T13 defer-max
        float mnew = fmaxf(m_run, mt);
        al = __expf(m_run - mnew);
        m_run = mnew;
        int base = (lane & 48) + ((lane & 48) >> 2);
#pragma unroll
        for (int r = 0; r < 4; ++r) {
          float alr = __shfl(al, base + r, 64);
#pragma unroll
          for (int db = 0; db < 4; ++db) acc_o[db][r] *= alr;
        }
      }

      float sum = 0.f;
#pragma unroll
      for (int cb = 0; cb < 4; ++cb) {
        float p0 = __expf(s[cb][0]-m_run), p1 = __expf(s[cb][1]-m_run);
        float p2 = __expf(s[cb][2]-m_run), p3 = __expf(s[cb][3]-m_run);
        sum += (p0+p1)+(p2+p3);
        unsigned long long pk =
            (unsigned long long)((unsigned int)f2b(p0) | ((unsigned int)f2b(p1)<<16)) |
            ((unsigned long long)((unsigned int)f2b(p2) | ((unsigned int)f2b(p3)<<16)) << 32);
        int col8 = cb*2 + (g>>1);
        int dst = (wq0 + sub)*64 + ((col8 ^ (sub&7))<<3) + ((g&1)<<2);
        *(unsigned long long*)&Ps[dst] = pk;
      }
      sum += __shfl_xor(sum, 16, 64);
      sum += __shfl_xor(sum, 32, 64);
      l_run = l_run*al + sum;

      __builtin_amdgcn_s_setprio(1);
#pragma unroll
      for (int kk = 0; kk < 2; ++kk) {
        bf16x8 pa = *(const bf16x8*)&Ps[(wq0 + sub)*64 + (((4*kk+g) ^ (sub&7))<<3)];
#pragma unroll
        for (int db = 0; db < 4; ++db) {
          int drow = db*16 + sub;
          bf16x8 vf = *(const bf16x8*)&vtb[drow*64 + (((4*kk+g) ^ (drow&7))<<3)];
          acc_o[db] = __builtin_amdgcn_mfma_f32_16x16x32_bf16(pa, vf, acc_o[db], 0, 0, 0);
        }
      }
      __builtin_amdgcn_s_setprio(0);
    }
    asm volatile("s_barrier" ::: "memory");
    cur ^= 1;
  }
#undef ATTN_STAGE

  // ---- tail: 2 extra keys ----
  const int qrow_mine = wq0 + sub;
  const int qpos_mine = qtb*128 + qrow_mine;
  float e1 = 0.f, e2 = 0.f;
  {
    const float* k1p = cache_k + ((size_t)((B_ + b)*H_ + h)*Q_ + qpos_mine)*HD_ + g*16;
    const u16*   kfp = Yb + (size_t)(b*Q_ + qpos_mine)*QKVN_ + H_*HD_ + (h/NREP_)*HD_ + g*16;
    float qv[16];
#pragma unroll
    for (int half = 0; half < 2; ++half) {
      int kb = 2*g + half;
      bf16x8 qq = *(const bf16x8*)&Qs[qrow_mine*64 + ((kb ^ (qrow_mine&7))<<3)];
#pragma unroll
      for (int i = 0; i < 8; ++i) qv[half*8 + i] = b2f(((u16)qq[i]));
    }
    float4 kf4a = *(const float4*)kfp;
    float4 kf4b = *(const float4*)(kfp + 8);
    const u16* kf16a = (const u16*)&kf4a;
    const u16* kf16b = (const u16*)&kf4b;
#pragma unroll
    for (int c = 0; c < 4; ++c) {
      float4 kv1 = *(const float4*)(k1p + 4*c);
      e1 += qv[4*c]*kv1.x + qv[4*c+1]*kv1.y + qv[4*c+2]*kv1.z + qv[4*c+3]*kv1.w;
    }
#pragma unroll
    for (int i = 0; i < 8; ++i) {
      e2 += qv[i]   * b2f(kf16a[i]);
      e2 += qv[8+i] * b2f(kf16b[i]);
    }
  }
  e1 += __shfl_xor(e1, 16, 64); e1 += __shfl_xor(e1, 32, 64);
  e2 += __shfl_xor(e2, 16, 64); e2 += __shfl_xor(e2, 32, 64);

#pragma unroll
  for (int r = 0; r < 4; ++r) {
    int row = 4*g + r;
    int src = (lane & 48) | row;
    float e1r = __shfl(e1, src, 64);
    float e2r = __shfl(e2, src, 64);
    float m_r = __shfl(m_run, src, 64);
    float l_r = __shfl(l_run, src, 64);
    float mnew = fmaxf(m_r, fmaxf(e1r, e2r));
    float alr = __expf(m_r - mnew);
    float w1  = __expf(e1r - mnew);
    float w2  = __expf(e2r - mnew);
    float linv = 1.f / (l_r*alr + w1 + w2);
    int qpos = qtb*128 + wq0 + row;
    const float* v1p = cache_v + ((size_t)((B_ + b)*H_ + h)*Q_ + qpos)*HD_;
    const u16*   vfp = Yb + (size_t)(b*Q_ + qpos)*QKVN_ + (H_*HD_ + KVH_*HD_) + (h/NREP_)*HD_;
    u16* op = AOb + (size_t)(b*Q_ + qpos)*AOW_ + h*HD_;
#pragma unroll
    for (int db = 0; db < 4; ++db) {
      int d = db*16 + sub;
      float o = (acc_o[db][r]*alr + w1*v1p[d] + w2*b2f(vfp[d])) * linv;
      op[d] = f2b(o);
    }
  }
}

extern "C" void kernel_launch(void* const* d_in, const int* in_sizes, int n_in,
                              void* d_out, int out_size, void* d_ws, size_t ws_size,
                              hipStream_t stream) {
  const float* hidden  = (const float*)d_in[0];
  const float* Wq      = (const float*)d_in[1];
  const float* Wk      = (const float*)d_in[2];
  const float* Wv      = (const float*)d_in[3];
  const float* Wo      = (const float*)d_in[4];   // [HS][H*HD]
  const float* cache_k = (const float*)d_in[5];
  const float* cache_v = (const float*)d_in[6];
  const int*   pos_ids = (const int*)d_in[8];
  float* out = (float*)d_out;

  char* ws = (char*)d_ws;
  u16* Yb  = (u16*)ws;  ws += (size_t)M_ * QKVN_ * 2;
  u16* Xb  = (u16*)ws;  ws += (size_t)M_ * KIN_ * 2;
  u16* Wb  = (u16*)ws;  ws += (size_t)QKVN_ * KIN_ * 2;
  u16* Wob = (u16*)ws;  ws += (size_t)HS_ * AOW_ * 2;
  u16* Kb  = (u16*)ws;  ws += (size_t)B_*H_*Q_*64 * 2;
  u16* Vtb = (u16*)ws;  ws += (size_t)B_*H_*Q_*64 * 2;
  u16* AOb = Xb;                                           // Xb dead after QKV GEMM

  cast_all<<<dim3(2048), 256, 0, stream>>>(hidden, Wq, Wk, Wv, Wo, Xb, Wb, Wob);
  cast_kv<<<dim3(16, 64), 256, 0, stream>>>(cache_k, cache_v, Kb, Vtb);

  // QKV GEMM with fused RoPE epilogue: grid 48x16 = 768 blocks
  gemm_nt<true><<<dim3(QKVN_/64, M_/128), 256, 0, stream>>>(Xb, Wb, (void*)Yb, KIN_, QKVN_, pos_ids);
  // attention: 512 blocks x 512 threads
  attn_mfma<<<dim3(512), 512, 0, stream>>>(Yb, Kb, Vtb, cache_k, cache_v, AOb);
  // Wo GEMM: grid 32x16 = 512 blocks, fp32 out
  gemm_nt<false><<<dim3(HS_/64, M_/128), 256, 0, stream>>>(AOb, Wob, (void*)out, AOW_, HS_, nullptr);
}

// Round 10
// 162.346 us; speedup vs baseline: 8.8549x; 1.0369x over previous
//
#include <hip/hip_runtime.h>
#include <hip/hip_bf16.h>
#include <math.h>

#define B_    2
#define Q_    1024
#define H_    32
#define KVH_  8
#define HD_   64
#define HS_   2048
#define NREP_ 4
#define KIN_  (2*HS_)            // 4096
#define M_    (B_*Q_)            // 2048
#define QKVN_ (H_*HD_ + 2*KVH_*HD_)  // 3072
#define AOW_  (H_*HD_)           // 2048
#define SCALE_ 0.125f            // 1/sqrt(64)

typedef __attribute__((ext_vector_type(8))) short bf16x8;
typedef __attribute__((ext_vector_type(4))) float f32x4;
typedef unsigned short u16;

static __device__ __forceinline__ u16 f2b(float f) {
  union { float f; unsigned int u; } c; c.f = f;
  unsigned int r = (c.u + 0x7fffu + ((c.u >> 16) & 1u)) >> 16;
  return (u16)r;
}
static __device__ __forceinline__ float b2f(u16 s) {
  union { unsigned int u; float f; } c;
  c.u = ((unsigned int)s) << 16;
  return c.f;
}
static __device__ __forceinline__ unsigned long long pack4s(float4 v, float sc) {
  return (unsigned long long)f2b(v.x*sc) |
         ((unsigned long long)f2b(v.y*sc) << 16) |
         ((unsigned long long)f2b(v.z*sc) << 32) |
         ((unsigned long long)f2b(v.w*sc) << 48);
}

#define GLOAD(SRC, DST) __builtin_amdgcn_global_load_lds( \
    (const __attribute__((address_space(1))) void*)(SRC), \
    (__attribute__((address_space(3))) void*)(DST), 16, 0, 0)

// ---------------- merged prep: K/V transpose-cast (blocks 0..1023) + flat casts ----------------
__global__ __launch_bounds__(256) void prep_kernel(
    const float* __restrict__ hidden, const float* __restrict__ Wq,
    const float* __restrict__ Wk, const float* __restrict__ Wv,
    const float* __restrict__ Wo,
    const float* __restrict__ k0, const float* __restrict__ v0,
    u16* __restrict__ Xb, u16* __restrict__ Wb, u16* __restrict__ Wob,
    u16* __restrict__ Kb, u16* __restrict__ Vtb)
{
  __shared__ float Vs[64][65];
  const int bx = blockIdx.x;
  const int t = threadIdx.x;
  if (bx < 1024) {
    // ---- cache K/V -> bf16 attn-ready swizzled layouts ----
    const int kt = bx & 15, bh = bx >> 4;
    const int r = t >> 2, seg = t & 3;
    {
      const float* sp = k0 + ((size_t)bh*Q_ + (kt<<6) + r)*64;
      u16* dp = Kb + ((size_t)bh*Q_ + (kt<<6) + r)*64;
#pragma unroll
      for (int c2 = 2*seg; c2 < 2*seg+2; ++c2) {
        int ca = c2 ^ (r & 7);
        float4 a = *(const float4*)(sp + ca*8);
        float4 b = *(const float4*)(sp + ca*8 + 4);
        unsigned long long o[2] = {pack4s(a,1.f), pack4s(b,1.f)};
        *(float4*)(dp + c2*8) = *(const float4*)o;
      }
    }
    {
      const float* sp = v0 + ((size_t)bh*Q_ + (kt<<6) + r)*64 + seg*16;
#pragma unroll
      for (int c = 0; c < 4; ++c) {
        float4 v = *(const float4*)(sp + 4*c);
        Vs[r][seg*16 + 4*c + 0] = v.x; Vs[r][seg*16 + 4*c + 1] = v.y;
        Vs[r][seg*16 + 4*c + 2] = v.z; Vs[r][seg*16 + 4*c + 3] = v.w;
      }
    }
    __syncthreads();
    {
      const int d = r;
      u16* dp = Vtb + ((size_t)bh*64 + d)*Q_ + (kt<<6);
#pragma unroll
      for (int c2 = 2*seg; c2 < 2*seg+2; ++c2) {
        int ca = c2 ^ (d & 7);
        u16 o[8];
#pragma unroll
        for (int j = 0; j < 8; ++j) o[j] = f2b(Vs[ca*8 + j][d]);
        *(float4*)(dp + c2*8) = *(const float4*)o;
      }
    }
  } else {
    // ---- flat fp32 -> bf16 casts, grid-strided over 2048 blocks ----
    const int U0 = 1048576;            // hidden (2048*4096/8)
    const int U1 = U0 + 1048576;       // +Wq
    const int U2 = U1 + 262144;        // +Wk    (512*4096/8)
    const int U3 = U2 + 262144;        // +Wv
    const int U4 = U3 + 524288;        // +Wo    (2048*2048/8)
    for (int u = (bx - 1024)*256 + t; u < U4; u += 2048*256) {
      const float* src; u16* dst;
      if (u < U0)      { src = hidden + (size_t)u*8;   dst = Xb + (size_t)u*8; }
      else if (u < U1) { src = Wq + (size_t)(u-U0)*8;  dst = Wb + (size_t)(u-U0)*8; }
      else if (u < U2) { src = Wk + (size_t)(u-U1)*8;  dst = Wb + (size_t)2048*KIN_ + (size_t)(u-U1)*8; }
      else if (u < U3) { src = Wv + (size_t)(u-U2)*8;  dst = Wb + (size_t)2560*KIN_ + (size_t)(u-U2)*8; }
      else             { src = Wo + (size_t)(u-U3)*8;  dst = Wob + (size_t)(u-U3)*8; }
      float4 a = *(const float4*)src;
      float4 bb = *(const float4*)(src + 4);
      unsigned long long o[2] = {pack4s(a, 1.f), pack4s(bb, 1.f)};
      *(float4*)dst = *(const float4*)o;
    }
  }
}

// ---------------- bf16 NT MFMA GEMM, 128x64, BK=64, dbuf; QKV mode fuses RoPE ----------------
template<bool QKV>
__global__ __launch_bounds__(256, 3) void gemm_nt(
    const u16* __restrict__ A, const u16* __restrict__ W,
    void* __restrict__ Cv, int K, int ldc, const int* __restrict__ pos_ids)
{
  __shared__ u16 As[2*128*64];   // 32 KB (reused as fp32 exchange in epilogue)
  __shared__ u16 Bs[2*64*64];    // 16 KB
  const int m0 = blockIdx.y << 7, n0 = blockIdx.x << 6;
  const int t = threadIdx.x;
  const int wave = t >> 6, lane = t & 63;
  const int wr = wave >> 1, wc = wave & 1;

  f32x4 acc[4][2] = {};

  const int lrow8 = lane >> 3;
  const int lcsw  = ((lane & 7) ^ lrow8) * 8;
  const int fr    = lane & 15;
  const int g     = lane >> 4;

#define GEMM_STAGE(BUF, K0) do { \
    _Pragma("unroll") \
    for (int p = 0; p < 4; ++p) { \
      int rbase = p * 32 + wave * 8; \
      GLOAD(A + (size_t)(m0 + rbase + lrow8) * K + (K0) + lcsw, \
            As + (BUF)*8192 + rbase * 64); \
    } \
    _Pragma("unroll") \
    for (int p = 0; p < 2; ++p) { \
      int rbase = p * 32 + wave * 8; \
      GLOAD(W + (size_t)(n0 + rbase + lrow8) * K + (K0) + lcsw, \
            Bs + (BUF)*4096 + rbase * 64); \
    } \
  } while(0)

  GEMM_STAGE(0, 0);
  int cur = 0;
  for (int k0 = 0; k0 < K; k0 += 64) {
    if (k0 + 64 < K) {
      GEMM_STAGE(cur ^ 1, k0 + 64);
      asm volatile("s_waitcnt vmcnt(6)" ::: "memory");
    } else {
      asm volatile("s_waitcnt vmcnt(0)" ::: "memory");
    }
    asm volatile("s_barrier" ::: "memory");

    const u16* Ab = As + cur*8192;
    const u16* Bb = Bs + cur*4096;
    bf16x8 af[4][2], bfr[2][2];
#pragma unroll
    for (int kk = 0; kk < 2; ++kk) {
      int ck = kk * 4 + g;
#pragma unroll
      for (int mi = 0; mi < 4; ++mi) {
        int row = wr * 64 + mi * 16 + fr;
        af[mi][kk] = *(const bf16x8*)(Ab + row * 64 + ((ck ^ (row & 7)) << 3));
      }
#pragma unroll
      for (int ni = 0; ni < 2; ++ni) {
        int row = wc * 32 + ni * 16 + fr;
        bfr[ni][kk] = *(const bf16x8*)(Bb + row * 64 + ((ck ^ (row & 7)) << 3));
      }
    }
    __builtin_amdgcn_s_setprio(1);
#pragma unroll
    for (int kk = 0; kk < 2; ++kk)
#pragma unroll
      for (int mi = 0; mi < 4; ++mi)
#pragma unroll
        for (int ni = 0; ni < 2; ++ni)
          acc[mi][ni] = __builtin_amdgcn_mfma_f32_16x16x32_bf16(af[mi][kk], bfr[ni][kk], acc[mi][ni], 0, 0, 0);
    __builtin_amdgcn_s_setprio(0);
    asm volatile("s_barrier" ::: "memory");
    cur ^= 1;
  }
#undef GEMM_STAGE

  if (QKV && n0 < 2560) {
    // ---- fused RoPE epilogue: pair (d, d+32) exchange via LDS, fast trig ----
    float* xch = (float*)As;   // 128 x 64 fp32 = 32 KB
    __syncthreads();
#pragma unroll
    for (int mi = 0; mi < 4; ++mi)
#pragma unroll
      for (int ni = 0; ni < 2; ++ni)
#pragma unroll
        for (int r = 0; r < 4; ++r)
          xch[(wr*64 + mi*16 + g*4 + r)*64 + wc*32 + ni*16 + (lane & 15)] = acc[mi][ni][r];
    __syncthreads();
    const bool isq = (n0 < 2048);
    u16* outp = (u16*)Cv;
    // inv(d) = 10000^(-d/32); inv(d+16) = inv(d) * 10000^(-1/2) = inv(d)*0.01
    const float inv0 = exp2f(-0.4152410118609203f * (float)(lane & 15));
    const float invs[2] = {inv0, inv0 * 0.01f};
#pragma unroll
    for (int mi = 0; mi < 4; ++mi) {
#pragma unroll
      for (int r = 0; r < 4; ++r) {
        int rl = wr*64 + mi*16 + g*4 + r;
        int m = m0 + rl;
        float p = (float)(pos_ids[m] + 2);
#pragma unroll
        for (int ni = 0; ni < 2; ++ni) {
          float f = p * invs[ni];
          float s, c;
          __sincosf(f, &s, &c);
          float mine = acc[mi][ni][r];
          float part = xch[rl*64 + ((wc^1)*32 + ni*16 + (lane & 15))];
          float outv = (wc == 0) ? (mine*c - part*s) : (mine*c + part*s);
          if (isq) outv *= SCALE_;
          outp[(size_t)m * ldc + n0 + wc*32 + ni*16 + (lane & 15)] = f2b(outv);
        }
      }
    }
  } else {
#pragma unroll
    for (int mi = 0; mi < 4; ++mi) {
      int rbase = m0 + wr * 64 + mi * 16 + g * 4;
#pragma unroll
      for (int ni = 0; ni < 2; ++ni) {
        int col = n0 + wc * 32 + ni * 16 + (lane & 15);
#pragma unroll
        for (int r = 0; r < 4; ++r) {
          if (QKV) ((u16*)Cv)[(size_t)(rbase + r) * ldc + col] = f2b(acc[mi][ni][r]);
          else     ((float*)Cv)[(size_t)(rbase + r) * ldc + col] = acc[mi][ni][r];
        }
      }
    }
  }
}

// ---------------- MFMA flash attention: QBLK=128, 8 waves, DMA K/V, dbuf ----------------
__global__ __launch_bounds__(512, 4) void attn_mfma(
    const u16* __restrict__ Yb,         // [M_][3072] bf16, rope applied, q scaled
    const u16* __restrict__ Kb,         // [bh][Q][64] swizzled bf16
    const u16* __restrict__ Vtb,        // [bh][64][Q] swizzled bf16
    const float* __restrict__ cache_k,  // [2][B][H][Q][64] fp32
    const float* __restrict__ cache_v,
    u16* __restrict__ AOb)              // [M_][2048] bf16
{
  __shared__ u16 Qs[128*64];   // 16 KB
  __shared__ u16 Ps[128*64];   // 16 KB
  __shared__ u16 Ks[2*64*64];  // 16 KB
  __shared__ u16 Vt[2*64*64];  // 16 KB  (total 64 KB)

  const int bid = blockIdx.x;
  const int xcd = bid & 7, within = bid >> 3;
  const int w8 = within & 7;
  const int qtb = (w8 & 1) ? (7 - (w8 >> 1)) : (w8 >> 1);   // balanced order
  const int pair = xcd * 8 + (within >> 3);
  const int h = pair >> 1, b = pair & 1;
  const int bh = b * H_ + h;

  const int t = threadIdx.x;
  const int wave = t >> 6, lane = t & 63;
  const int g = lane >> 4, sub = lane & 15;
  const int wq0 = wave * 16;                 // 0..112
  const int srow = lane >> 3;                // 0..7
  const int scc  = lane & 7;

  const u16* KbT = Kb + (size_t)bh * Q_ * 64;
  const u16* VtT = Vtb + (size_t)bh * 64 * Q_;

#define ATTN_STAGE(BUF, KT) do { \
    int r_ = wave*8 + srow; \
    GLOAD(KbT + (size_t)(((KT)<<6) + r_)*64 + scc*8, Ks + (BUF)*4096 + wave*512); \
    GLOAD(VtT + (size_t)r_*Q_ + ((KT)<<6) + scc*8,   Vt + (BUF)*4096 + wave*512); \
  } while(0)

  // stage Q (128 rows, 2 rounds), swizzled at source
  {
#pragma unroll
    for (int p = 0; p < 2; ++p) {
      int r = p*64 + wave*8 + srow;
      GLOAD(Yb + (size_t)(b*Q_ + qtb*128 + r)*QKVN_ + h*64 + ((scc ^ (r&7))<<3),
            Qs + p*4096 + wave*512);
    }
  }
  ATTN_STAGE(0, 0);
  asm volatile("s_waitcnt vmcnt(2)" ::: "memory");   // Q landed; stage0 in flight
  asm volatile("s_barrier" ::: "memory");

  bf16x8 qb[2];
#pragma unroll
  for (int kk = 0; kk < 2; ++kk) {
    int row = wq0 + sub;
    qb[kk] = *(const bf16x8*)&Qs[row*64 + (((4*kk+g) ^ (row&7))<<3)];
  }

  float m_run = -3e38f, l_run = 0.f;
  f32x4 acc_o[4] = {};
  int cur = 0;
  const int nkt = 2*qtb + 2;

  for (int kt = 0; kt < nkt; ++kt) {
    if (kt + 1 < nkt) {
      ATTN_STAGE(cur ^ 1, kt + 1);
      asm volatile("s_waitcnt vmcnt(2)" ::: "memory");
    } else {
      asm volatile("s_waitcnt vmcnt(0)" ::: "memory");
    }
    asm volatile("s_barrier" ::: "memory");

    // wave-uniform skip of fully-masked tiles (causal)
    if (kt*64 <= qtb*128 + wq0 + 15) {
      const u16* ksb = Ks + cur*4096;
      const u16* vtb = Vt + cur*4096;

      f32x4 s[4] = {};
      __builtin_amdgcn_s_setprio(1);
#pragma unroll
      for (int kk = 0; kk < 2; ++kk) {
        int kb = 4*kk + g;
#pragma unroll
        for (int cb = 0; cb < 4; ++cb) {
          int krow = cb*16 + sub;
          bf16x8 kf = *(const bf16x8*)&ksb[krow*64 + ((kb ^ (krow&7))<<3)];
          s[cb] = __builtin_amdgcn_mfma_f32_16x16x32_bf16(kf, qb[kk], s[cb], 0, 0, 0);
        }
      }
      __builtin_amdgcn_s_setprio(0);

      if (kt >= 2*qtb) {   // diagonal region: apply causal mask
#pragma unroll
        for (int cb = 0; cb < 4; ++cb)
#pragma unroll
          for (int r = 0; r < 4; ++r)
            if (kt*64 + cb*16 + 4*g + r > qtb*128 + wq0 + sub) s[cb][r] = -3e38f;
      }

      float mt = -3e38f;
#pragma unroll
      for (int cb = 0; cb < 4; ++cb)
#pragma unroll
        for (int r = 0; r < 4; ++r) mt = fmaxf(mt, s[cb][r]);
      mt = fmaxf(mt, __shfl_xor(mt, 16, 64));
      mt = fmaxf(mt, __shfl_xor(mt, 32, 64));

      float al = 1.0f;
      if (__any(mt > m_run + 8.f)) {       // T13 defer-max
        float mnew = fmaxf(m_run, mt);
        al = __expf(m_run - mnew);
        m_run = mnew;
        int base = (lane & 48) + ((lane & 48) >> 2);
#pragma unroll
        for (int r = 0; r < 4; ++r) {
          float alr = __shfl(al, base + r, 64);
#pragma unroll
          for (int db = 0; db < 4; ++db) acc_o[db][r] *= alr;
        }
      }

      float sum = 0.f;
#pragma unroll
      for (int cb = 0; cb < 4; ++cb) {
        float p0 = __expf(s[cb][0]-m_run), p1 = __expf(s[cb][1]-m_run);
        float p2 = __expf(s[cb][2]-m_run), p3 = __expf(s[cb][3]-m_run);
        sum += (p0+p1)+(p2+p3);
        unsigned long long pk =
            (unsigned long long)((unsigned int)f2b(p0) | ((unsigned int)f2b(p1)<<16)) |
            ((unsigned long long)((unsigned int)f2b(p2) | ((unsigned int)f2b(p3)<<16)) << 32);
        int col8 = cb*2 + (g>>1);
        int dst = (wq0 + sub)*64 + ((col8 ^ (sub&7))<<3) + ((g&1)<<2);
        *(unsigned long long*)&Ps[dst] = pk;
      }
      sum += __shfl_xor(sum, 16, 64);
      sum += __shfl_xor(sum, 32, 64);
      l_run = l_run*al + sum;

      __builtin_amdgcn_s_setprio(1);
#pragma unroll
      for (int kk = 0; kk < 2; ++kk) {
        bf16x8 pa = *(const bf16x8*)&Ps[(wq0 + sub)*64 + (((4*kk+g) ^ (sub&7))<<3)];
#pragma unroll
        for (int db = 0; db < 4; ++db) {
          int drow = db*16 + sub;
          bf16x8 vf = *(const bf16x8*)&vtb[drow*64 + (((4*kk+g) ^ (drow&7))<<3)];
          acc_o[db] = __builtin_amdgcn_mfma_f32_16x16x32_bf16(pa, vf, acc_o[db], 0, 0, 0);
        }
      }
      __builtin_amdgcn_s_setprio(0);
    }
    asm volatile("s_barrier" ::: "memory");
    cur ^= 1;
  }
#undef ATTN_STAGE

  // ---- tail: 2 extra keys ----
  const int qrow_mine = wq0 + sub;
  const int qpos_mine = qtb*128 + qrow_mine;
  float e1 = 0.f, e2 = 0.f;
  {
    const float* k1p = cache_k + ((size_t)((B_ + b)*H_ + h)*Q_ + qpos_mine)*HD_ + g*16;
    const u16*   kfp = Yb + (size_t)(b*Q_ + qpos_mine)*QKVN_ + H_*HD_ + (h/NREP_)*HD_ + g*16;
    float qv[16];
#pragma unroll
    for (int half = 0; half < 2; ++half) {
      int kb = 2*g + half;
      bf16x8 qq = *(const bf16x8*)&Qs[qrow_mine*64 + ((kb ^ (qrow_mine&7))<<3)];
#pragma unroll
      for (int i = 0; i < 8; ++i) qv[half*8 + i] = b2f(((u16)qq[i]));
    }
    float4 kf4a = *(const float4*)kfp;
    float4 kf4b = *(const float4*)(kfp + 8);
    const u16* kf16a = (const u16*)&kf4a;
    const u16* kf16b = (const u16*)&kf4b;
#pragma unroll
    for (int c = 0; c < 4; ++c) {
      float4 kv1 = *(const float4*)(k1p + 4*c);
      e1 += qv[4*c]*kv1.x + qv[4*c+1]*kv1.y + qv[4*c+2]*kv1.z + qv[4*c+3]*kv1.w;
    }
#pragma unroll
    for (int i = 0; i < 8; ++i) {
      e2 += qv[i]   * b2f(kf16a[i]);
      e2 += qv[8+i] * b2f(kf16b[i]);
    }
  }
  e1 += __shfl_xor(e1, 16, 64); e1 += __shfl_xor(e1, 32, 64);
  e2 += __shfl_xor(e2, 16, 64); e2 += __shfl_xor(e2, 32, 64);

#pragma unroll
  for (int r = 0; r < 4; ++r) {
    int row = 4*g + r;
    int src = (lane & 48) | row;
    float e1r = __shfl(e1, src, 64);
    float e2r = __shfl(e2, src, 64);
    float m_r = __shfl(m_run, src, 64);
    float l_r = __shfl(l_run, src, 64);
    float mnew = fmaxf(m_r, fmaxf(e1r, e2r));
    float alr = __expf(m_r - mnew);
    float w1  = __expf(e1r - mnew);
    float w2  = __expf(e2r - mnew);
    float linv = 1.f / (l_r*alr + w1 + w2);
    int qpos = qtb*128 + wq0 + row;
    const float* v1p = cache_v + ((size_t)((B_ + b)*H_ + h)*Q_ + qpos)*HD_;
    const u16*   vfp = Yb + (size_t)(b*Q_ + qpos)*QKVN_ + (H_*HD_ + KVH_*HD_) + (h/NREP_)*HD_;
    u16* op = AOb + (size_t)(b*Q_ + qpos)*AOW_ + h*HD_;
#pragma unroll
    for (int db = 0; db < 4; ++db) {
      int d = db*16 + sub;
      float o = (acc_o[db][r]*alr + w1*v1p[d] + w2*b2f(vfp[d])) * linv;
      op[d] = f2b(o);
    }
  }
}

extern "C" void kernel_launch(void* const* d_in, const int* in_sizes, int n_in,
                              void* d_out, int out_size, void* d_ws, size_t ws_size,
                              hipStream_t stream) {
  const float* hidden  = (const float*)d_in[0];
  const float* Wq      = (const float*)d_in[1];
  const float* Wk      = (const float*)d_in[2];
  const float* Wv      = (const float*)d_in[3];
  const float* Wo      = (const float*)d_in[4];   // [HS][H*HD]
  const float* cache_k = (const float*)d_in[5];
  const float* cache_v = (const float*)d_in[6];
  const int*   pos_ids = (const int*)d_in[8];
  float* out = (float*)d_out;

  char* ws = (char*)d_ws;
  u16* Yb  = (u16*)ws;  ws += (size_t)M_ * QKVN_ * 2;
  u16* Xb  = (u16*)ws;  ws += (size_t)M_ * KIN_ * 2;
  u16* Wb  = (u16*)ws;  ws += (size_t)QKVN_ * KIN_ * 2;
  u16* Wob = (u16*)ws;  ws += (size_t)HS_ * AOW_ * 2;
  u16* Kb  = (u16*)ws;  ws += (size_t)B_*H_*Q_*64 * 2;
  u16* Vtb = (u16*)ws;  ws += (size_t)B_*H_*Q_*64 * 2;
  u16* AOb = Xb;                                           // Xb dead after QKV GEMM

  prep_kernel<<<dim3(3072), 256, 0, stream>>>(
      hidden, Wq, Wk, Wv, Wo, cache_k, cache_v, Xb, Wb, Wob, Kb, Vtb);

  // QKV GEMM with fused RoPE epilogue: grid 48x16 = 768 blocks
  gemm_nt<true><<<dim3(QKVN_/64, M_/128), 256, 0, stream>>>(Xb, Wb, (void*)Yb, KIN_, QKVN_, pos_ids);
  // attention: 512 blocks x 512 threads
  attn_mfma<<<dim3(512), 512, 0, stream>>>(Yb, Kb, Vtb, cache_k, cache_v, AOb);
  // Wo GEMM: grid 32x16 = 512 blocks, fp32 out
  gemm_nt<false><<<dim3(HS_/64, M_/128), 256, 0, stream>>>(AOb, Wob, (void*)out, AOW_, HS_, nullptr);
}